// Round 17
// baseline (778.826 us; speedup 1.0000x reference)
//
#include <hip/hip_runtime.h>
#include <hip/hip_bf16.h>

typedef __bf16 bf16;
typedef __bf16 bf16x8 __attribute__((ext_vector_type(8)));
typedef __bf16 bf16x4 __attribute__((ext_vector_type(4)));
typedef float f32x4 __attribute__((ext_vector_type(4)));
typedef unsigned u32x4 __attribute__((ext_vector_type(4)));

#define DEVI static __device__ __forceinline__

DEVI float sigmoidf_(float x){ return 1.0f/(1.0f+__expf(-x)); }
DEVI float eluf_(float x){ return x>0.f ? x : (__expf(x)-1.f); }
DEVI f32x4 mfma16(bf16x8 a, bf16x8 b, f32x4 c){ return __builtin_amdgcn_mfma_f32_16x16x32_bf16(a,b,c,0,0,0); }
DEVI f32x4 mfma8(long a, long b, f32x4 c){ return __builtin_amdgcn_mfma_f32_16x16x32_fp8_fp8(a,b,c,0,0,0); }
DEVI unsigned pack2_(float a, float b){
    union { bf16 v[2]; unsigned u; } t; t.v[0]=(bf16)a; t.v[1]=(bf16)b; return t.u;
}
DEVI unsigned long long pack4_(float a, float b, float c, float d){
    union { bf16 v[4]; unsigned long long u; } t;
    t.v[0]=(bf16)a; t.v[1]=(bf16)b; t.v[2]=(bf16)c; t.v[3]=(bf16)d; return t.u;
}
DEVI unsigned cvtfp8x4_(float a, float b, float c, float d){
    int v = __builtin_amdgcn_cvt_pk_fp8_f32(a, b, 0, false);
    v = __builtin_amdgcn_cvt_pk_fp8_f32(c, d, v, true);
    return (unsigned)v;
}

#define B_ 8192
#define F_ 100
#define FP 112
#define H_ 128
#define KC_ 12800
#define SPLIT_ 4
#define FP8SC 16.0f

#define SWZ(r,bc) ((bc) ^ (((r)&7)<<4))

// ---------------- mega weight prep ----------------
DEVI void dotrans_(float (*t)[33], const float* in, bf16* out, int R, int C, int bx, int by, int tid){
    int c0 = bx*32, r0 = by*32;
    int tc = tid & 31, tr = tid >> 5;
    #pragma unroll
    for (int i=0;i<4;i++){
        int r = tr + i*8;
        t[r][tc] = in[(size_t)(r0+r)*C + c0 + tc];
    }
    __syncthreads();
    #pragma unroll
    for (int i=0;i<4;i++){
        int ro = tr + i*8;
        out[(size_t)(c0+ro)*R + r0 + tc] = (bf16)t[tc][ro];
    }
}

__global__ void k_prep_all(const float* __restrict__ qw, const float* __restrict__ qb,
                           const float* __restrict__ kw, const float* __restrict__ kb,
                           const float* __restrict__ tw, const float* __restrict__ tb,
                           const float* __restrict__ a1w, const float* __restrict__ vw,
                           const float* __restrict__ a2w, const float* __restrict__ c2w,
                           const float* __restrict__ c3w,
                           bf16* __restrict__ mextT, float* __restrict__ sigt, float* __restrict__ cconst,
                           bf16* __restrict__ wvT, bf16* __restrict__ wa2t,
                           bf16* __restrict__ c2wt, bf16* __restrict__ c3wt){
    __shared__ float t[32][33];
    const float rsc = 0.08838834764831845f;
    int blk = blockIdx.x, tid = threadIdx.x;
    if (blk < 9){
        #pragma unroll 1
        for (int e=0; e<8; ++e){
            int idx = e*256 + tid;
            int n = blk*16 + (idx>>7), h = idx&127;
            float acc = 0.f;
            if (n < 128){
                for (int d=0; d<128; ++d) acc += qw[h*128+d]*kw[n*128+d];
            } else if (n == 128){
                for (int d=0; d<128; ++d) acc += qw[h*128+d]*kb[d];
            } else if (n == 129){
                for (int d=0; d<128; ++d) acc += kw[h*128+d]*qb[d];
            }
            mextT[n*128+h] = (bf16)(acc*rsc);
        }
    } else if (blk == 9){
        if (tid < 128){
            float acc = 0.f;
            for (int h=0; h<128; ++h) acc += (tw[h]+tb[h]) * a1w[h*128+tid];
            sigt[tid] = sigmoidf_(acc);
        } else if (tid == 128){
            float acc = 0.f;
            for (int d=0; d<128; ++d) acc += qb[d]*kb[d];
            cconst[0] = acc*rsc;
        }
    } else if (blk < 26){
        int i = blk-10; dotrans_(t, vw, wvT, 128,128, i&3, i>>2, tid);
    } else if (blk < 42){
        int i = blk-26; dotrans_(t, a2w, wa2t, 128,128, i&3, i>>2, tid);
    } else if (blk < 298){
        int i = blk-42; dotrans_(t, c2w, c2wt, 512,512, i&15, i>>4, tid);
    } else {
        int i = blk-298; dotrans_(t, c3w, c3wt, 512,256, i&7, i>>3, tid);
    }
}

// compact kappa: bijection on [0,12800)
DEVI int kappa_(int k){
    int f = k>>7, h = k&127;
    if (f < 96)
        return (((f>>4)<<3) | (h>>4))*256 + ((f&15)>>2)*64 + (h&15)*4 + (f&3);
    else
        return 12288 + (h>>4)*64 + (h&15)*4 + (f&3);
}

// ---------------- merged: c1w kappa-fp8 prep (blocks 0..6399) + gatt GEMM (6400..13567) ----------------
__global__ __launch_bounds__(256,2) void k_gk(
    const float* __restrict__ c1w, unsigned char* __restrict__ c1wtk8,
    const float* __restrict__ feat, const float* __restrict__ emb,
    const bf16* __restrict__ wa2t, const float* __restrict__ a2b,
    const float* __restrict__ a3w, const float* __restrict__ sigt,
    float* __restrict__ attg)
{
    __shared__ char A[37888];
    int blk = blockIdx.x, tid = threadIdx.x;
    if (blk < 6400){
        float (*t)[33] = (float(*)[33])A;
        const int C = 512;
        int c0 = (blk&15)*32, r0 = (blk>>4)*32;
        int tc = tid & 31, tr = tid >> 5;
        #pragma unroll
        for (int i=0;i<4;i++){
            int r = tr + i*8;
            t[r][tc] = c1w[(size_t)(r0+r)*C + c0 + tc];
        }
        __syncthreads();
        #pragma unroll
        for (int i=0;i<4;i++){
            int ro = tr + i*8;
            float x = t[tc][ro]*FP8SC;
            int v = __builtin_amdgcn_cvt_pk_fp8_f32(x, x, 0, false);
            c1wtk8[(size_t)(c0+ro)*KC_ + kappa_(r0+tc)] = (unsigned char)v;
        }
        return;
    }
    bf16 (*sAt)[72] = (bf16(*)[72])A;
    bf16 (*sBt)[72] = (bf16(*)[72])(A + 18432);
    float (*sRed)[128] = (float(*)[128])(A + 36864);
    int w=tid>>6, lane=tid&63, l15=lane&15, l4=lane>>4;
    int m0 = (blk-6400)*128;
    int wr = w>>1, wc = w&1;
    f32x4 acc[4][4];
    #pragma unroll
    for(int mi=0;mi<4;mi++)
        #pragma unroll
        for(int ni=0;ni<4;ni++) acc[mi][ni] = (f32x4){0.f,0.f,0.f,0.f};

    #pragma unroll 1
    for (int k0=0; k0<128; k0+=64){
        __syncthreads();
        #pragma unroll
        for (int t4=0; t4<4; t4++){
            int t = tid + t4*256;
            int row=t>>3, col=(t&7)*8;
            int gr = m0+row;
            int bb = gr/112, ff = gr - bb*112;
            bf16x8 o;
            if (ff < F_){
                float fv = feat[(size_t)bb*F_ + ff];
                const float* ep = emb + ff*H_ + k0 + col;
                f32x4 e0 = *(const f32x4*)ep;
                f32x4 e1 = *(const f32x4*)(ep+4);
                o[0]=(bf16)(fv*e0[0]); o[1]=(bf16)(fv*e0[1]); o[2]=(bf16)(fv*e0[2]); o[3]=(bf16)(fv*e0[3]);
                o[4]=(bf16)(fv*e1[0]); o[5]=(bf16)(fv*e1[1]); o[6]=(bf16)(fv*e1[2]); o[7]=(bf16)(fv*e1[3]);
            } else {
                #pragma unroll
                for (int e=0;e<8;e++) o[e]=(bf16)0.f;
            }
            *(bf16x8*)&sAt[row][col] = o;
            *(bf16x8*)&sBt[row][col] = *(const bf16x8*)(wa2t + row*H_ + k0 + col);
        }
        __syncthreads();
        #pragma unroll
        for(int ks=0;ks<2;ks++){
            bf16x8 af[4], bfr[4];
            #pragma unroll
            for(int mi=0;mi<4;mi++) af[mi] = *(const bf16x8*)&sAt[wr*64+mi*16+l15][ks*32+l4*8];
            #pragma unroll
            for(int ni=0;ni<4;ni++) bfr[ni] = *(const bf16x8*)&sBt[wc*64+ni*16+l15][ks*32+l4*8];
            #pragma unroll
            for(int mi=0;mi<4;mi++)
                #pragma unroll
                for(int ni=0;ni<4;ni++)
                    acc[mi][ni] = mfma16(af[mi], bfr[ni], acc[mi][ni]);
        }
    }
    float sg[4], ab[4], a3[4];
    #pragma unroll
    for (int ni=0;ni<4;ni++){
        int n = wc*64 + ni*16 + l15;
        sg[ni]=sigt[n]; ab[ni]=a2b[n]; a3[ni]=a3w[n];
    }
    #pragma unroll
    for (int mi=0;mi<4;mi++){
        float sj[4] = {0.f,0.f,0.f,0.f};
        #pragma unroll
        for (int ni=0;ni<4;ni++){
            #pragma unroll
            for (int j=0;j<4;j++){
                float u = sigmoidf_(acc[mi][ni][j] + ab[ni]);
                float t = sg[ni] + u;
                t = t>0.f ? t : 0.f;
                sj[j] += t*a3[ni];
            }
        }
        #pragma unroll
        for (int j=0;j<4;j++){
            float v = sj[j];
            #pragma unroll
            for (int m=1;m<16;m<<=1) v += __shfl_xor(v,m,16);
            sj[j]=v;
        }
        if (l15==0){
            #pragma unroll
            for (int j=0;j<4;j++) sRed[wc][wr*64+mi*16+l4*4+j] = sj[j];
        }
    }
    __syncthreads();
    if (tid < 128) attg[(size_t)m0 + tid] = sRed[0][tid] + sRed[1][tid];
}

// ---------------- fused per-batch attention: 2 batches/block, persistent sMext ----------------
// LDS (81792 B, 2 blocks/CU):
//   Lm [0,32768)      sMext 128x256 SWZ (persistent across both batches)
//   Ln [32768,61440)  sNx 112x256 SWZ  -> (after B6, per batch) sVT 128x224 SWZ
//   [61440,79872)     sP[8][16][72]; aliases sFeat/normP (slots 0-2), sAw (slot 7)
//   [79872,81792)     sNorm[128], sAlpha[112], sBeta[112], sInv[8][16]
__global__ __launch_bounds__(512,2) void k_attn2(
    const float* __restrict__ feat, const float* __restrict__ emb,
    const bf16* __restrict__ mextT, const bf16* __restrict__ wvT,
    const float* __restrict__ vb, const float* __restrict__ cconst,
    const float* __restrict__ attg,
    unsigned char* __restrict__ xxb, bf16* __restrict__ xtb)
{
    __shared__ char L[81792];
    char* Lm = L;
    char* Ln = L + 32768;
    float* sFeat  = (float*)(L+61440);
    float* normP  = (float*)(L+62336);   // [8][128] f32
    float* sAw    = (float*)(L+77568);   // wave-7 sP slot
    float* sNorm  = (float*)(L+79872);
    float* sAlpha = (float*)(L+80384);
    float* sBeta  = (float*)(L+80832);
    float* sInv   = (float*)(L+81280);   // [8][16]

    int tid = threadIdx.x, w = tid>>6, lane = tid&63;
    int l15 = lane&15, l4 = lane>>4;
    bf16 (*sP)[72] = (bf16(*)[72])(L + 61440 + w*2304);

    bf16x8 awv[4];
    #pragma unroll
    for (int kc=0;kc<4;kc++)
        awv[kc] = *(const bf16x8*)(wvT + (w*16+l15)*H_ + kc*32 + l4*8);
    float vbr = vb[w*16+l15];

    // stage sMext once (persistent; sVT now lives in Ln so Lm survives both batches)
    #pragma unroll 2
    for (int v = tid; v < 128*16; v += 512){
        int n = v >> 4, cg = (v & 15) * 8;
        *(u32x4*)(Lm + n*256 + SWZ(n, cg*2)) = *(const u32x4*)(mextT + n*128 + cg);
    }
    const float cc = cconst[0];

    #pragma unroll 1
    for (int bi=0; bi<2; ++bi){
        int b = blockIdx.x*2 + bi;
        __syncthreads();   // head: previous batch's sP/Ln reads complete

        if (tid < FP) sFeat[tid] = (tid<F_) ? feat[(size_t)b*F_+tid] : 0.f;
        if (w==0){
            const float* ag = attg + (size_t)b*FP;
            float a0 = (lane<F_)? ag[lane] : -1e30f;
            float a1 = (lane+64<F_)? ag[lane+64] : -1e30f;
            float m = fmaxf(a0,a1);
            #pragma unroll
            for(int s=1;s<64;s<<=1) m = fmaxf(m, __shfl_xor(m,s,64));
            float e0 = (lane<F_)? __expf(a0-m):0.f;
            float e1 = (lane+64<F_)? __expf(a1-m):0.f;
            float s = e0+e1;
            #pragma unroll
            for(int t=1;t<64;t<<=1) s += __shfl_xor(s,t,64);
            float inv = 1.f/s;
            if (lane<FP) sAw[lane] = e0*inv;
            if (lane+64<FP) sAw[lane+64] = e1*inv;
        }
        __syncthreads();   // B1

        int hp = (tid&63)*2, gg = tid>>6;
        {
            float fa0=0.f, fa1=0.f;
            #pragma unroll 4
            for (int it=0; it<13; ++it){
                int f = gg + 8*it;
                if (f < F_){
                    float2 e2 = *(const float2*)(emb + f*H_ + hp);
                    float v0 = sFeat[f]*e2.x, v1 = sFeat[f]*e2.y;
                    fa0 += v0*v0; fa1 += v1*v1;
                }
            }
            *(float2*)(normP + gg*128 + hp) = make_float2(fa0, fa1);
        }
        __syncthreads();   // B2
        if (tid < 128){
            float s = 0.f;
            #pragma unroll
            for (int g2=0; g2<8; ++g2) s += normP[g2*128 + tid];
            sNorm[tid] = sqrtf(s);
        }
        __syncthreads();   // B3

        {
            float rn0 = __builtin_amdgcn_rcpf(sNorm[hp]);
            float rn1 = __builtin_amdgcn_rcpf(sNorm[hp+1]);
            #pragma unroll 4
            for (int it=0; it<13; ++it){
                int f = gg + 8*it;
                if (f < F_){
                    float2 e2 = *(const float2*)(emb + f*H_ + hp);
                    *(unsigned*)(Ln + f*256 + SWZ(f, hp*2)) = pack2_(sFeat[f]*e2.x*rn0, sFeat[f]*e2.y*rn1);
                }
            }
            for (int z=tid; z<768; z+=512){
                int f = 100 + (z>>6), hz = (z&63)*2;
                *(unsigned*)(Ln + f*256 + SWZ(f, hz*2)) = 0u;
            }
        }
        __syncthreads();   // B4

        int mt = w;

        if (mt < 7){
            bf16x8 bfr8[4];
            #pragma unroll
            for (int kc=0;kc<4;kc++)
                bfr8[kc] = *(const bf16x8*)(mextT + (128+(l15&1))*H_ + kc*32 + l4*8);
            f32x4 acc = {0.f,0.f,0.f,0.f};
            #pragma unroll
            for (int kc=0;kc<4;kc++){
                bf16x8 a = *(const bf16x8*)(Ln + (mt*16+l15)*256 + SWZ(mt*16+l15, (kc*32+l4*8)*2));
                acc = mfma16(a, bfr8[kc], acc);
            }
            if (l15==0){
                #pragma unroll
                for (int j=0;j<4;j++) sAlpha[mt*16+l4*4+j] = acc[j];
            }
            if (l15==1){
                #pragma unroll
                for (int j=0;j<4;j++) sBeta[mt*16+l4*4+j] = acc[j];
            }
        }
        __syncthreads();   // B5

        unsigned long long uexB[3];
        if (mt < 7){
            bf16x8 afxi[4];
            #pragma unroll
            for (int kc=0;kc<4;kc++)
                afxi[kc] = *(const bf16x8*)(Ln + (mt*16+l15)*256 + SWZ(mt*16+l15, (kc*32+l4*8)*2));
            f32x4 sc[7];
            #pragma unroll
            for (int gt=0; gt<7; gt++) sc[gt] = (f32x4){0.f,0.f,0.f,0.f};
            #pragma unroll 1
            for (int p=0; p<2; p++){
                #pragma unroll 2
                for (int nt4=0; nt4<4; nt4++){
                    int nt = p*4 + nt4;
                    bf16x8 bw[4];
                    #pragma unroll
                    for (int kc=0;kc<4;kc++)
                        bw[kc] = *(const bf16x8*)(Lm + (nt*16+l15)*256 + SWZ(nt*16+l15, (kc*32+l4*8)*2));
                    f32x4 d = {0.f,0.f,0.f,0.f};
                    #pragma unroll
                    for (int kc=0;kc<4;kc++) d = mfma16(bw[kc], afxi[kc], d);   // D[n][f]
                    *(unsigned long long*)(&sP[l15][nt4*16 + l4*4]) = pack4_(d[0],d[1],d[2],d[3]);
                }
                bf16x8 afs0 = *(const bf16x8*)&sP[l15][l4*8];
                bf16x8 afs1 = *(const bf16x8*)&sP[l15][32+l4*8];
                #pragma unroll
                for (int gt=0; gt<7; gt++){
                    int r = gt*16+l15;
                    bf16x8 b0 = *(const bf16x8*)(Ln + r*256 + SWZ(r, (p*64 + l4*8)*2));
                    bf16x8 b1 = *(const bf16x8*)(Ln + r*256 + SWZ(r, (p*64 + 32 + l4*8)*2));
                    sc[gt] = mfma16(b0, afs0, sc[gt]);   // D[g][f]
                    sc[gt] = mfma16(b1, afs1, sc[gt]);
                }
            }
            float aj = sAlpha[mt*16+l15];
            float rs = 0.f;
            #pragma unroll
            for (int gt=0; gt<7; gt++){
                f32x4 bt4 = *(const f32x4*)&sBeta[gt*16+l4*4];
                float e[4];
                #pragma unroll
                for (int j=0;j<4;j++){
                    int g = gt*16 + l4*4 + j;
                    float val = sc[gt][j] + aj + bt4[j] + cc;
                    e[j] = (g<F_) ? __expf(sigmoidf_(val)) : 0.f;
                    rs += e[j];
                }
                if (gt < 4)
                    *(unsigned long long*)(&sP[l15][gt*16 + l4*4]) = pack4_(e[0],e[1],e[2],e[3]);
                else
                    uexB[gt-4] = pack4_(e[0],e[1],e[2],e[3]);
            }
            rs += __shfl_xor(rs, 16, 64);
            rs += __shfl_xor(rs, 32, 64);
            if (l4 == 0) sInv[w*16 + l15] = 1.f/rs;
        } else {
            int h = lane;
            float a0=0.f, a1=0.f;
            #pragma unroll 4
            for (int f=0; f<F_; ++f){
                float awf = sAw[f];
                a0 += awf * (float)*(const bf16*)(Ln + f*256 + SWZ(f, h*2));
                a1 += awf * (float)*(const bf16*)(Ln + f*256 + SWZ(f, (h+64)*2));
            }
            xtb[(size_t)b*H_ + h]      = (bf16)(a0 * sNorm[h]);
            xtb[(size_t)b*H_ + h + 64] = (bf16)(a1 * sNorm[h+64]);
        }

        unsigned long long vpku[7];
        #pragma unroll
        for (int gt=0; gt<7; gt++){
            f32x4 acc = {0.f,0.f,0.f,0.f};
            #pragma unroll
            for (int kc=0;kc<4;kc++){
                int r = gt*16+l15;
                bf16x8 a = *(const bf16x8*)(Ln + r*256 + SWZ(r, (kc*32+l4*8)*2));
                acc = mfma16(a, awv[kc], acc);
            }
            vpku[gt] = pack4_(acc[0]+vbr, acc[1]+vbr, acc[2]+vbr, acc[3]+vbr);
        }
        __syncthreads();   // B6: all Ln(nx) reads complete

        {   // sVT into Ln, stride 224 (Lm/sMext preserved for next batch)
            int hrow = w*16 + l15;
            #pragma unroll
            for (int gt=0; gt<7; gt++)
                *(unsigned long long*)(Ln + hrow*224 + SWZ(hrow, gt*32 + l4*8)) = vpku[gt];
        }
        __syncthreads();   // B7

        if (mt < 7){
            bf16x8 ap0 = *(const bf16x8*)&sP[l15][l4*8];
            bf16x8 ap1 = *(const bf16x8*)&sP[l15][32+l4*8];
            f32x4 acc8[8];
            #pragma unroll
            for (int ht=0;ht<8;ht++) acc8[ht] = (f32x4){0.f,0.f,0.f,0.f};
            #pragma unroll
            for (int ht=0; ht<8; ht++){
                int r = ht*16+l15;
                bf16x8 bv0 = *(const bf16x8*)(Ln + r*224 + SWZ(r, (l4*8)*2));
                bf16x8 bv1 = *(const bf16x8*)(Ln + r*224 + SWZ(r, (32+l4*8)*2));
                acc8[ht] = mfma16(ap0, bv0, acc8[ht]);
                acc8[ht] = mfma16(ap1, bv1, acc8[ht]);
            }
            #pragma unroll
            for (int gt=4; gt<7; gt++)
                *(unsigned long long*)(&sP[l15][(gt-4)*16 + l4*4]) = uexB[gt-4];
            *(unsigned long long*)(&sP[l15][48 + l4*4]) = 0ull;
            bf16x8 ap2 = *(const bf16x8*)&sP[l15][l4*8];
            bf16x8 ap3 = *(const bf16x8*)&sP[l15][32+l4*8];
            #pragma unroll
            for (int ht=0; ht<8; ht++){
                int r = ht*16+l15;
                int c2 = 64+l4*8;
                int c3 = 96+l4*8;  if (c3 >= 112) c3 = 96;
                bf16x8 bv2 = *(const bf16x8*)(Ln + r*224 + SWZ(r, c2*2));
                bf16x8 bv3 = *(const bf16x8*)(Ln + r*224 + SWZ(r, c3*2));
                acc8[ht] = mfma16(ap2, bv2, acc8[ht]);
                acc8[ht] = mfma16(ap3, bv3, acc8[ht]);
            }
            float fs[4];
            #pragma unroll
            for (int j=0;j<4;j++) fs[j] = sInv[w*16 + l4*4 + j] * FP8SC;
            #pragma unroll
            for (int ht=0; ht<8; ht++){
                unsigned u = cvtfp8x4_(acc8[ht][0]*fs[0], acc8[ht][1]*fs[1], acc8[ht][2]*fs[2], acc8[ht][3]*fs[3]);
                if (mt < 6){
                    *(unsigned*)(xxb + (size_t)b*KC_ + (mt*8+ht)*256 + lane*4) = u;
                } else if (l4 == 0){
                    *(unsigned*)(xxb + (size_t)b*KC_ + 12288 + ht*64 + l15*4) = u;
                }
            }
        }
    }
}

// ---------------- fp8 split-K GEMM: 128x256 tile, 512 thr, bf16 partials ----------------
__global__ __launch_bounds__(512,2) void k_gemm_fp8(const unsigned char* __restrict__ A,
        const unsigned char* __restrict__ Bt, bf16* __restrict__ part, int M, int N, int K, int KS)
{
    __shared__ unsigned char sA[128][144];
    __shared__ unsigned char sB[256][144];
    int tid=threadIdx.x, w=tid>>6, lane=tid&63, l15=lane&15, l4=lane>>4;
    int m0 = blockIdx.y*128, n0 = blockIdx.x*256;
    int kbeg = blockIdx.z*KS, kend = kbeg + KS;
    int wr = w>>2, wc = w&3;
    f32x4 acc[4][4];
    #pragma unroll
    for(int mi=0;mi<4;mi++)
        #pragma unroll
        for(int ni=0;ni<4;ni++) acc[mi][ni] = (f32x4){0.f,0.f,0.f,0.f};

    for (int k0=kbeg; k0<kend; k0+=128){
        __syncthreads();
        #pragma unroll
        for (int t2=0;t2<2;t2++){
            int t = tid + t2*512;
            int row=t>>3, col=(t&7)*16;
            *(u32x4*)&sA[row][col] = *(const u32x4*)(A + (size_t)(m0+row)*K + k0 + col);
        }
        #pragma unroll
        for (int t4=0;t4<4;t4++){
            int t = tid + t4*512;
            int row=t>>3, col=(t&7)*16;
            *(u32x4*)&sB[row][col] = *(const u32x4*)(Bt + (size_t)(n0+row)*K + k0 + col);
        }
        __syncthreads();
        #pragma unroll
        for(int ks=0;ks<4;ks++){
            long af[4], bfr[4];
            #pragma unroll
            for(int mi=0;mi<4;mi++) af[mi] = *(const long*)&sA[wr*64+mi*16+l15][ks*32+l4*8];
            #pragma unroll
            for(int ni=0;ni<4;ni++) bfr[ni] = *(const long*)&sB[wc*64+ni*16+l15][ks*32+l4*8];
            #pragma unroll
            for(int mi=0;mi<4;mi++)
                #pragma unroll
                for(int ni=0;ni<4;ni++)
                    acc[mi][ni] = mfma8(af[mi], bfr[ni], acc[mi][ni]);
        }
    }
    bf16* pz = part + (size_t)blockIdx.z*M*N;
    #pragma unroll
    for(int mi=0;mi<4;mi++)
        #pragma unroll
        for(int ni=0;ni<4;ni++){
            int col = n0 + wc*64 + ni*16 + l15;
            #pragma unroll
            for(int j=0;j<4;j++){
                int row = m0 + wr*64 + mi*16 + l4*4 + j;
                pz[(size_t)row*N + col] = (bf16)acc[mi][ni][j];
            }
        }
}

// reduce SPLIT bf16 partials + bias + ELU -> bf16
__global__ void k_c1fin(const bf16* __restrict__ part, const float* __restrict__ bias,
                        bf16* __restrict__ out){
    const size_t MN = (size_t)B_*512;
    size_t e0 = ((size_t)blockIdx.x*256 + threadIdx.x)*4;
    bf16x4 p0 = *(const bf16x4*)(part + e0);
    bf16x4 p1 = *(const bf16x4*)(part + MN + e0);
    bf16x4 p2 = *(const bf16x4*)(part + 2*MN + e0);
    bf16x4 p3 = *(const bf16x4*)(part + 3*MN + e0);
    f32x4 bb = *(const f32x4*)(bias + (e0 & 511));
    const float ds = 1.0f/(FP8SC*FP8SC);
    float s0 = ((float)p0[0]+(float)p1[0]+(float)p2[0]+(float)p3[0])*ds + bb[0];
    float s1 = ((float)p0[1]+(float)p1[1]+(float)p2[1]+(float)p3[1])*ds + bb[1];
    float s2 = ((float)p0[2]+(float)p1[2]+(float)p2[2]+(float)p3[2])*ds + bb[2];
    float s3 = ((float)p0[3]+(float)p1[3]+(float)p2[3]+(float)p3[3])*ds + bb[3];
    unsigned long long u = pack4_(eluf_(s0), eluf_(s1), eluf_(s2), eluf_(s3));
    *(unsigned long long*)(out + e0) = u;
}

// ---------------- generic tiled GEMM (c2, c3), BK=128 ----------------
template<int BN, bool ELU>
__global__ __launch_bounds__(256,2) void k_gemm(const bf16* __restrict__ A, const bf16* __restrict__ Bt,
        const float* __restrict__ bias, bf16* __restrict__ out, int M, int N, int K)
{
    __shared__ bf16 sAt[128][136];
    __shared__ bf16 sBt[BN][136];
    int tid=threadIdx.x, w=tid>>6, lane=tid&63, l15=lane&15, l4=lane>>4;
    int m0 = blockIdx.y*128, n0 = blockIdx.x*BN;
    constexpr int MI = (BN==128)?4:2;
    constexpr int NI = 4;
    int wr = (BN==128)? (w>>1) : w;
    int wc = (BN==128)? (w&1) : 0;
    f32x4 acc[MI][NI];
    #pragma unroll
    for(int mi=0;mi<MI;mi++)
        #pragma unroll
        for(int ni=0;ni<NI;ni++) acc[mi][ni] = (f32x4){0.f,0.f,0.f,0.f};

    for (int k0=0; k0<K; k0+=128){
        __syncthreads();
        for (int t=tid; t<128*16; t+=256){
            int row=t>>4, col=(t&15)*8;
            *(bf16x8*)&sAt[row][col] = *(const bf16x8*)(A + (size_t)(m0+row)*K + k0 + col);
        }
        for (int t=tid; t<BN*16; t+=256){
            int row=t>>4, col=(t&15)*8;
            *(bf16x8*)&sBt[row][col] = *(const bf16x8*)(Bt + (size_t)(n0+row)*K + k0 + col);
        }
        __syncthreads();
        #pragma unroll
        for(int ks=0;ks<4;ks++){
            bf16x8 af[MI], bfr[NI];
            #pragma unroll
            for(int mi=0;mi<MI;mi++) af[mi] = *(const bf16x8*)&sAt[wr*(MI*16)+mi*16+l15][ks*32+l4*8];
            #pragma unroll
            for(int ni=0;ni<NI;ni++) bfr[ni] = *(const bf16x8*)&sBt[wc*64+ni*16+l15][ks*32+l4*8];
            #pragma unroll
            for(int mi=0;mi<MI;mi++)
                #pragma unroll
                for(int ni=0;ni<NI;ni++)
                    acc[mi][ni] = mfma16(af[mi], bfr[ni], acc[mi][ni]);
        }
    }
    #pragma unroll
    for(int mi=0;mi<MI;mi++)
        #pragma unroll
        for(int ni=0;ni<NI;ni++){
            int col = n0 + wc*64 + ni*16 + l15;
            float bc = bias[col];
            #pragma unroll
            for(int j=0;j<4;j++){
                int row = m0 + wr*(MI*16) + mi*16 + l4*4 + j;
                float v = acc[mi][ni][j] + bc;
                if (ELU) v = eluf_(v);
                out[(size_t)row*N + col] = (bf16)v;
            }
        }
}

// ---------------- merged tails ----------------
__global__ __launch_bounds__(256,2) void k_tails(const bf16* __restrict__ c3o,
    const float* __restrict__ c4w, const float* __restrict__ c4b,
    const float* __restrict__ c5w, const float* __restrict__ c5b,
    const float* __restrict__ clw, const float* __restrict__ clb,
    const float* __restrict__ ctw, const float* __restrict__ ctb,
    const bf16* __restrict__ xtb,
    const float* __restrict__ u1w, const float* __restrict__ u1b,
    const float* __restrict__ u2w, const float* __restrict__ u2b,
    const float* __restrict__ u3w, const float* __restrict__ u3b,
    const float* __restrict__ u4w, const float* __restrict__ u4b,
    const float* __restrict__ tlw, const float* __restrict__ tlb,
    const float* __restrict__ utw, const float* __restrict__ utb, float* __restrict__ outp)
{
    __shared__ char A[58880];
    int tid = threadIdx.x, blk = blockIdx.x;
    int r0 = (blk>>1)*32;
    if ((blk & 1) == 0){
        float (*sA)[260] = (float(*)[260])A;
        float (*sB)[132] = (float(*)[132])(A + 33280);
        float (*sC)[68]  = (float(*)[68])(A + 50176);
        for (int v=tid; v<32*64; v+=256){
            int r=v>>6, c=(v&63)*4;
            bf16x4 x = *(const bf16x4*)(c3o + (size_t)(r0+r)*256 + c);
            sA[r][c]=(float)x[0]; sA[r][c+1]=(float)x[1]; sA[r][c+2]=(float)x[2]; sA[r][c+3]=(float)x[3];
        }
        __syncthreads();
        {
            int j = tid&127, rb = tid>>7;
            float acc[16];
            #pragma unroll
            for (int i=0;i<16;i++) acc[i]=c4b[j];
            #pragma unroll 4
            for (int h=0;h<256;h++){
                float wv = c4w[h*128+j];
                #pragma unroll
                for (int i=0;i<16;i++) acc[i] += sA[2*i+rb][h]*wv;
            }
            #pragma unroll
            for (int i=0;i<16;i++) sB[2*i+rb][j] = eluf_(acc[i]);
        }
        __syncthreads();
        {
            int j = tid&63, rb = tid>>6;
            float acc[8];
            #pragma unroll
            for (int i=0;i<8;i++) acc[i]=c5b[j];
            #pragma unroll 4
            for (int h=0;h<128;h++){
                float wv = c5w[h*64+j];
                #pragma unroll
                for (int i=0;i<8;i++) acc[i] += sB[4*i+rb][h]*wv;
            }
            #pragma unroll
            for (int i=0;i<8;i++) sC[4*i+rb][j] = eluf_(acc[i]);
        }
        __syncthreads();
        if (tid < 32){
            float r1 = clb[0], r2 = ctb[0];
            #pragma unroll 8
            for (int k=0;k<64;k++){ float v = sC[tid][k]; r1 += v*clw[k]; r2 += v*ctw[k]; }
            int row = r0 + tid;
            outp[row] = r1;
            outp[B_ + row] = sigmoidf_(r1);
            outp[(size_t)2*B_ + row] = r2;
        }
    } else {
        float (*sA)[132] = (float(*)[132])A;
        float (*sB)[132] = (float(*)[132])(A + 16896);
        float (*sC)[68]  = (float(*)[68])(A + 33792);
        float (*sD)[36]  = (float(*)[36])(A + 42496);
        float (*sE)[20]  = (float(*)[20])(A + 47104);
        for (int v=tid; v<32*32; v+=256){
            int r=v>>5, c=(v&31)*4;
            bf16x4 x = *(const bf16x4*)(xtb + (size_t)(r0+r)*128 + c);
            sA[r][c]=(float)x[0]; sA[r][c+1]=(float)x[1]; sA[r][c+2]=(float)x[2]; sA[r][c+3]=(float)x[3];
        }
        __syncthreads();
        {
            int j = tid&127, rb = tid>>7;
            float acc[16];
            #pragma unroll
            for (int i=0;i<16;i++) acc[i]=u1b[j];
            #pragma unroll 4
            for (int h=0;h<128;h++){
                float wv = u1w[h*128+j];
                #pragma unroll
                for (int i=0;i<16;i++) acc[i] += sA[2*i+rb][h]*wv;
            }
            #pragma unroll
            for (int i=0;i<16;i++) sB[2*i+rb][j] = eluf_(acc[i]);
        }
        __syncthreads();
        {
            int j = tid&63, rb = tid>>6;
            float acc[8];
            #pragma unroll
            for (int i=0;i<8;i++) acc[i]=u2b[j];
            #pragma unroll 4
            for (int h=0;h<128;h++){
                float wv = u2w[h*64+j];
                #pragma unroll
                for (int i=0;i<8;i++) acc[i] += sB[4*i+rb][h]*wv;
            }
            #pragma unroll
            for (int i=0;i<8;i++) sC[4*i+rb][j] = eluf_(acc[i]);
        }
        __syncthreads();
        {
            int j = tid&31, rb = tid>>5;
            float acc[4];
            #pragma unroll
            for (int i=0;i<4;i++) acc[i]=u3b[j];
            #pragma unroll 4
            for (int h=0;h<64;h++){
                float wv = u3w[h*32+j];
                #pragma unroll
                for (int i=0;i<4;i++) acc[i] += sC[8*i+rb][h]*wv;
            }
            #pragma unroll
            for (int i=0;i<4;i++) sD[8*i+rb][j] = eluf_(acc[i]);
        }
        __syncthreads();
        {
            int j = tid&15, rb = tid>>4;
            float acc0=u4b[j], acc1=u4b[j];
            #pragma unroll 4
            for (int h=0;h<32;h++){
                float wv = u4w[h*16+j];
                acc0 += sD[rb][h]*wv;
                acc1 += sD[16+rb][h]*wv;
            }
            sE[rb][j] = eluf_(acc0);
            sE[16+rb][j] = eluf_(acc1);
        }
        __syncthreads();
        if (tid < 32){
            float r1 = tlb[0], r2 = utb[0];
            #pragma unroll
            for (int k=0;k<16;k++){ float v = sE[tid][k]; r1 += v*tlw[k]; r2 += v*utw[k]; }
            int row = r0 + tid;
            outp[(size_t)3*B_ + row] = r1;
            outp[(size_t)4*B_ + row] = sigmoidf_(r1);
            outp[(size_t)5*B_ + row] = r2;
        }
    }
}

extern "C" void kernel_launch(void* const* d_in, const int* in_sizes, int n_in,
                              void* d_out, int out_size, void* d_ws, size_t ws_size,
                              hipStream_t stream) {
    const float* feat=(const float*)d_in[0];
    const float* emb =(const float*)d_in[2];
    const float* t_w =(const float*)d_in[3]; const float* t_b=(const float*)d_in[4];
    const float* qw  =(const float*)d_in[5]; const float* qb =(const float*)d_in[6];
    const float* kw  =(const float*)d_in[7]; const float* kb =(const float*)d_in[8];
    const float* vw  =(const float*)d_in[9]; const float* vb =(const float*)d_in[10];
    const float* a1w =(const float*)d_in[11];
    const float* a2w =(const float*)d_in[12]; const float* a2b=(const float*)d_in[13];
    const float* a3w =(const float*)d_in[14];
    const float* c1w =(const float*)d_in[15]; const float* c1b=(const float*)d_in[16];
    const float* c2w =(const float*)d_in[17]; const float* c2b=(const float*)d_in[18];
    const float* c3w =(const float*)d_in[19]; const float* c3b=(const float*)d_in[20];
    const float* c4w =(const float*)d_in[21]; const float* c4b=(const float*)d_in[22];
    const float* c5w =(const float*)d_in[23]; const float* c5b=(const float*)d_in[24];
    const float* clw =(const float*)d_in[25]; const float* clb=(const float*)d_in[26];
    const float* ctw =(const float*)d_in[27]; const float* ctb=(const float*)d_in[28];
    const float* u1w =(const float*)d_in[29]; const float* u1b=(const float*)d_in[30];
    const float* u2w =(const float*)d_in[31]; const float* u2b=(const float*)d_in[32];
    const float* u3w =(const float*)d_in[33]; const float* u3b=(const float*)d_in[34];
    const float* u4w =(const float*)d_in[35]; const float* u4b=(const float*)d_in[36];
    const float* tlw =(const float*)d_in[37]; const float* tlb=(const float*)d_in[38];
    const float* utw =(const float*)d_in[39]; const float* utb=(const float*)d_in[40];
    float* outp = (float*)d_out;

    char* ws = (char*)d_ws;
    size_t off = 0;
    auto alloc = [&](size_t bytes)->char*{ char* p = ws + off; off += (bytes + 255) & ~(size_t)255; return p; };
    unsigned char* xxb = (unsigned char*)alloc((size_t)B_*KC_);
    bf16* part   = (bf16*)alloc((size_t)SPLIT_*B_*512*2);
    float* attg  = (float*)alloc((size_t)B_*FP*4);
    bf16* xtb    = (bf16*)alloc((size_t)B_*128*2);
    bf16* cbuf1  = (bf16*)alloc((size_t)B_*512*2);
    bf16* mextT  = (bf16*)alloc(144*128*2);
    bf16* wvT    = (bf16*)alloc(128*128*2);
    bf16* wa2t   = (bf16*)alloc(128*128*2);
    unsigned char* c1wtk8 = (unsigned char*)alloc((size_t)512*KC_);
    bf16* c2wt   = (bf16*)alloc((size_t)512*512*2);
    bf16* c3wt   = (bf16*)alloc((size_t)512*256*2);
    float* sigt  = (float*)alloc(128*4);
    float* cconst= (float*)alloc(4);
    bf16* cbuf2 = (bf16*)(xxb);
    bf16* cbuf3 = (bf16*)(xxb + (16u<<20));
    (void)ws_size; (void)in_sizes; (void)n_in; (void)out_size;

    k_prep_all<<<426,256,0,stream>>>(qw,qb,kw,kb,t_w,t_b,a1w, vw, a2w, c2w, c3w,
                                     mextT, sigt, cconst, wvT, wa2t, c2wt, c3wt);

    k_gk<<<13568,256,0,stream>>>(c1w, c1wtk8, feat, emb, wa2t, a2b, a3w, sigt, attg);

    k_attn2<<<B_/2,512,0,stream>>>(feat,emb,mextT,wvT,vb,cconst,attg, xxb, xtb);

    k_gemm_fp8<<<dim3(2,64,SPLIT_),512,0,stream>>>(xxb, c1wtk8, part, B_,512,KC_, KC_/SPLIT_);
    k_c1fin<<<4096,256,0,stream>>>(part, c1b, cbuf1);

    k_gemm<128,true><<<dim3(4,64),256,0,stream>>>(cbuf1, c2wt, c2b, cbuf2, B_,512,512);
    k_gemm<64,true><<<dim3(4,64),256,0,stream>>>(cbuf2, c3wt, c3b, cbuf3, B_,256,512);

    k_tails<<<512,256,0,stream>>>(cbuf3,c4w,c4b,c5w,c5b,clw,clb,ctw,ctb,
                                  xtb,u1w,u1b,u2w,u2b,u3w,u3b,u4w,u4b,tlw,tlb,utw,utb,outp);
}

// Round 18
// 632.005 us; speedup vs baseline: 1.2323x; 1.2323x over previous
//
#include <hip/hip_runtime.h>
#include <hip/hip_bf16.h>

typedef __bf16 bf16;
typedef __bf16 bf16x8 __attribute__((ext_vector_type(8)));
typedef __bf16 bf16x4 __attribute__((ext_vector_type(4)));
typedef float f32x4 __attribute__((ext_vector_type(4)));
typedef unsigned u32x4 __attribute__((ext_vector_type(4)));

#define DEVI static __device__ __forceinline__

DEVI float sigmoidf_(float x){ return 1.0f/(1.0f+__expf(-x)); }
DEVI float eluf_(float x){ return x>0.f ? x : (__expf(x)-1.f); }
DEVI f32x4 mfma16(bf16x8 a, bf16x8 b, f32x4 c){ return __builtin_amdgcn_mfma_f32_16x16x32_bf16(a,b,c,0,0,0); }
DEVI f32x4 mfma8(long a, long b, f32x4 c){ return __builtin_amdgcn_mfma_f32_16x16x32_fp8_fp8(a,b,c,0,0,0); }
DEVI unsigned pack2_(float a, float b){
    union { bf16 v[2]; unsigned u; } t; t.v[0]=(bf16)a; t.v[1]=(bf16)b; return t.u;
}
DEVI unsigned long long pack4_(float a, float b, float c, float d){
    union { bf16 v[4]; unsigned long long u; } t;
    t.v[0]=(bf16)a; t.v[1]=(bf16)b; t.v[2]=(bf16)c; t.v[3]=(bf16)d; return t.u;
}
DEVI unsigned cvtfp8x4_(float a, float b, float c, float d){
    int v = __builtin_amdgcn_cvt_pk_fp8_f32(a, b, 0, false);
    v = __builtin_amdgcn_cvt_pk_fp8_f32(c, d, v, true);
    return (unsigned)v;
}

#define B_ 8192
#define F_ 100
#define FP 112
#define H_ 128
#define KC_ 12800
#define SPLIT_ 4
#define FP8SC 16.0f

#define SWZ(r,bc) ((bc) ^ (((r)&7)<<4))

// ---------------- mega weight prep ----------------
DEVI void dotrans_(float (*t)[33], const float* in, bf16* out, int R, int C, int bx, int by, int tid){
    int c0 = bx*32, r0 = by*32;
    int tc = tid & 31, tr = tid >> 5;
    #pragma unroll
    for (int i=0;i<4;i++){
        int r = tr + i*8;
        t[r][tc] = in[(size_t)(r0+r)*C + c0 + tc];
    }
    __syncthreads();
    #pragma unroll
    for (int i=0;i<4;i++){
        int ro = tr + i*8;
        out[(size_t)(c0+ro)*R + r0 + tc] = (bf16)t[tc][ro];
    }
}

__global__ void k_prep_all(const float* __restrict__ qw, const float* __restrict__ qb,
                           const float* __restrict__ kw, const float* __restrict__ kb,
                           const float* __restrict__ tw, const float* __restrict__ tb,
                           const float* __restrict__ a1w, const float* __restrict__ vw,
                           const float* __restrict__ a2w, const float* __restrict__ c2w,
                           const float* __restrict__ c3w,
                           bf16* __restrict__ mextT, float* __restrict__ sigt, float* __restrict__ cconst,
                           bf16* __restrict__ wvT, bf16* __restrict__ wa2t,
                           bf16* __restrict__ c2wt, bf16* __restrict__ c3wt){
    __shared__ float t[32][33];
    const float rsc = 0.08838834764831845f;
    int blk = blockIdx.x, tid = threadIdx.x;
    if (blk < 9){
        #pragma unroll 1
        for (int e=0; e<8; ++e){
            int idx = e*256 + tid;
            int n = blk*16 + (idx>>7), h = idx&127;
            float acc = 0.f;
            if (n < 128){
                for (int d=0; d<128; ++d) acc += qw[h*128+d]*kw[n*128+d];
            } else if (n == 128){
                for (int d=0; d<128; ++d) acc += qw[h*128+d]*kb[d];
            } else if (n == 129){
                for (int d=0; d<128; ++d) acc += kw[h*128+d]*qb[d];
            }
            mextT[n*128+h] = (bf16)(acc*rsc);
        }
    } else if (blk == 9){
        if (tid < 128){
            float acc = 0.f;
            for (int h=0; h<128; ++h) acc += (tw[h]+tb[h]) * a1w[h*128+tid];
            sigt[tid] = sigmoidf_(acc);
        } else if (tid == 128){
            float acc = 0.f;
            for (int d=0; d<128; ++d) acc += qb[d]*kb[d];
            cconst[0] = acc*rsc;
        }
    } else if (blk < 26){
        int i = blk-10; dotrans_(t, vw, wvT, 128,128, i&3, i>>2, tid);
    } else if (blk < 42){
        int i = blk-26; dotrans_(t, a2w, wa2t, 128,128, i&3, i>>2, tid);
    } else if (blk < 298){
        int i = blk-42; dotrans_(t, c2w, c2wt, 512,512, i&15, i>>4, tid);
    } else {
        int i = blk-298; dotrans_(t, c3w, c3wt, 512,256, i&7, i>>3, tid);
    }
}

// compact kappa: bijection on [0,12800)
DEVI int kappa_(int k){
    int f = k>>7, h = k&127;
    if (f < 96)
        return (((f>>4)<<3) | (h>>4))*256 + ((f&15)>>2)*64 + (h&15)*4 + (f&3);
    else
        return 12288 + (h>>4)*64 + (h&15)*4 + (f&3);
}

// ---------------- merged: c1w kappa-fp8 prep (blocks 0..6399) + gatt GEMM (6400..13567) ----------------
__global__ __launch_bounds__(256,2) void k_gk(
    const float* __restrict__ c1w, unsigned char* __restrict__ c1wtk8,
    const float* __restrict__ feat, const float* __restrict__ emb,
    const bf16* __restrict__ wa2t, const float* __restrict__ a2b,
    const float* __restrict__ a3w, const float* __restrict__ sigt,
    float* __restrict__ attg)
{
    __shared__ char A[37888];
    int blk = blockIdx.x, tid = threadIdx.x;
    if (blk < 6400){
        float (*t)[33] = (float(*)[33])A;
        const int C = 512;
        int c0 = (blk&15)*32, r0 = (blk>>4)*32;
        int tc = tid & 31, tr = tid >> 5;
        #pragma unroll
        for (int i=0;i<4;i++){
            int r = tr + i*8;
            t[r][tc] = c1w[(size_t)(r0+r)*C + c0 + tc];
        }
        __syncthreads();
        #pragma unroll
        for (int i=0;i<4;i++){
            int ro = tr + i*8;
            float x = t[tc][ro]*FP8SC;
            int v = __builtin_amdgcn_cvt_pk_fp8_f32(x, x, 0, false);
            c1wtk8[(size_t)(c0+ro)*KC_ + kappa_(r0+tc)] = (unsigned char)v;
        }
        return;
    }
    bf16 (*sAt)[72] = (bf16(*)[72])A;
    bf16 (*sBt)[72] = (bf16(*)[72])(A + 18432);
    float (*sRed)[128] = (float(*)[128])(A + 36864);
    int w=tid>>6, lane=tid&63, l15=lane&15, l4=lane>>4;
    int m0 = (blk-6400)*128;
    int wr = w>>1, wc = w&1;
    f32x4 acc[4][4];
    #pragma unroll
    for(int mi=0;mi<4;mi++)
        #pragma unroll
        for(int ni=0;ni<4;ni++) acc[mi][ni] = (f32x4){0.f,0.f,0.f,0.f};

    #pragma unroll 1
    for (int k0=0; k0<128; k0+=64){
        __syncthreads();
        #pragma unroll
        for (int t4=0; t4<4; t4++){
            int t = tid + t4*256;
            int row=t>>3, col=(t&7)*8;
            int gr = m0+row;
            int bb = gr/112, ff = gr - bb*112;
            bf16x8 o;
            if (ff < F_){
                float fv = feat[(size_t)bb*F_ + ff];
                const float* ep = emb + ff*H_ + k0 + col;
                f32x4 e0 = *(const f32x4*)ep;
                f32x4 e1 = *(const f32x4*)(ep+4);
                o[0]=(bf16)(fv*e0[0]); o[1]=(bf16)(fv*e0[1]); o[2]=(bf16)(fv*e0[2]); o[3]=(bf16)(fv*e0[3]);
                o[4]=(bf16)(fv*e1[0]); o[5]=(bf16)(fv*e1[1]); o[6]=(bf16)(fv*e1[2]); o[7]=(bf16)(fv*e1[3]);
            } else {
                #pragma unroll
                for (int e=0;e<8;e++) o[e]=(bf16)0.f;
            }
            *(bf16x8*)&sAt[row][col] = o;
            *(bf16x8*)&sBt[row][col] = *(const bf16x8*)(wa2t + row*H_ + k0 + col);
        }
        __syncthreads();
        #pragma unroll
        for(int ks=0;ks<2;ks++){
            bf16x8 af[4], bfr[4];
            #pragma unroll
            for(int mi=0;mi<4;mi++) af[mi] = *(const bf16x8*)&sAt[wr*64+mi*16+l15][ks*32+l4*8];
            #pragma unroll
            for(int ni=0;ni<4;ni++) bfr[ni] = *(const bf16x8*)&sBt[wc*64+ni*16+l15][ks*32+l4*8];
            #pragma unroll
            for(int mi=0;mi<4;mi++)
                #pragma unroll
                for(int ni=0;ni<4;ni++)
                    acc[mi][ni] = mfma16(af[mi], bfr[ni], acc[mi][ni]);
        }
    }
    float sg[4], ab[4], a3[4];
    #pragma unroll
    for (int ni=0;ni<4;ni++){
        int n = wc*64 + ni*16 + l15;
        sg[ni]=sigt[n]; ab[ni]=a2b[n]; a3[ni]=a3w[n];
    }
    #pragma unroll
    for (int mi=0;mi<4;mi++){
        float sj[4] = {0.f,0.f,0.f,0.f};
        #pragma unroll
        for (int ni=0;ni<4;ni++){
            #pragma unroll
            for (int j=0;j<4;j++){
                float u = sigmoidf_(acc[mi][ni][j] + ab[ni]);
                float t = sg[ni] + u;
                t = t>0.f ? t : 0.f;
                sj[j] += t*a3[ni];
            }
        }
        #pragma unroll
        for (int j=0;j<4;j++){
            float v = sj[j];
            #pragma unroll
            for (int m=1;m<16;m<<=1) v += __shfl_xor(v,m,16);
            sj[j]=v;
        }
        if (l15==0){
            #pragma unroll
            for (int j=0;j<4;j++) sRed[wc][wr*64+mi*16+l4*4+j] = sj[j];
        }
    }
    __syncthreads();
    if (tid < 128) attg[(size_t)m0 + tid] = sRed[0][tid] + sRed[1][tid];
}

// ---------------- fused per-batch attention ----------------
__global__ __launch_bounds__(512,2) void k_attn2(
    const float* __restrict__ feat, const float* __restrict__ emb,
    const bf16* __restrict__ mextT, const bf16* __restrict__ wvT,
    const float* __restrict__ vb, const float* __restrict__ cconst,
    const float* __restrict__ attg,
    unsigned char* __restrict__ xxb, bf16* __restrict__ xtb)
{
    __shared__ char L[81792];
    char* Lm = L;
    char* Ln = L + 32768;
    float* sFeat  = (float*)(L+61440);
    float* normP  = (float*)(L+62336);   // [8][128] f32
    float* sAw    = (float*)(L+77568);   // wave-7 sP slot
    float* sNorm  = (float*)(L+79872);
    float* sAlpha = (float*)(L+80384);
    float* sBeta  = (float*)(L+80832);
    float* sInv   = (float*)(L+81280);   // [8][16]

    int b = blockIdx.x;
    int tid = threadIdx.x, w = tid>>6, lane = tid&63;
    int l15 = lane&15, l4 = lane>>4;
    bf16 (*sP)[72] = (bf16(*)[72])(L + 61440 + w*2304);

    bf16x8 awv[4];
    #pragma unroll
    for (int kc=0;kc<4;kc++)
        awv[kc] = *(const bf16x8*)(wvT + (w*16+l15)*H_ + kc*32 + l4*8);
    float vbr = vb[w*16+l15];

    #pragma unroll 2
    for (int v = tid; v < 128*16; v += 512){
        int n = v >> 4, cg = (v & 15) * 8;
        *(u32x4*)(Lm + n*256 + SWZ(n, cg*2)) = *(const u32x4*)(mextT + n*128 + cg);
    }
    if (tid < FP) sFeat[tid] = (tid<F_) ? feat[(size_t)b*F_+tid] : 0.f;
    if (w==0){
        const float* ag = attg + (size_t)b*FP;
        float a0 = (lane<F_)? ag[lane] : -1e30f;
        float a1 = (lane+64<F_)? ag[lane+64] : -1e30f;
        float m = fmaxf(a0,a1);
        #pragma unroll
        for(int s=1;s<64;s<<=1) m = fmaxf(m, __shfl_xor(m,s,64));
        float e0 = (lane<F_)? __expf(a0-m):0.f;
        float e1 = (lane+64<F_)? __expf(a1-m):0.f;
        float s = e0+e1;
        #pragma unroll
        for(int t=1;t<64;t<<=1) s += __shfl_xor(s,t,64);
        float inv = 1.f/s;
        if (lane<FP) sAw[lane] = e0*inv;
        if (lane+64<FP) sAw[lane+64] = e1*inv;
    }
    __syncthreads();   // B1

    int hp = (tid&63)*2, gg = tid>>6;
    {
        float fa0=0.f, fa1=0.f;
        #pragma unroll 4
        for (int it=0; it<13; ++it){
            int f = gg + 8*it;
            if (f < F_){
                float2 e2 = *(const float2*)(emb + f*H_ + hp);
                float v0 = sFeat[f]*e2.x, v1 = sFeat[f]*e2.y;
                fa0 += v0*v0; fa1 += v1*v1;
            }
        }
        *(float2*)(normP + gg*128 + hp) = make_float2(fa0, fa1);
    }
    __syncthreads();   // B2
    if (tid < 128){
        float s = 0.f;
        #pragma unroll
        for (int g2=0; g2<8; ++g2) s += normP[g2*128 + tid];
        sNorm[tid] = sqrtf(s);
    }
    __syncthreads();   // B3

    {
        float rn0 = __builtin_amdgcn_rcpf(sNorm[hp]);
        float rn1 = __builtin_amdgcn_rcpf(sNorm[hp+1]);
        #pragma unroll 4
        for (int it=0; it<13; ++it){
            int f = gg + 8*it;
            if (f < F_){
                float2 e2 = *(const float2*)(emb + f*H_ + hp);
                *(unsigned*)(Ln + f*256 + SWZ(f, hp*2)) = pack2_(sFeat[f]*e2.x*rn0, sFeat[f]*e2.y*rn1);
            }
        }
        for (int z=tid; z<768; z+=512){
            int f = 100 + (z>>6), hz = (z&63)*2;
            *(unsigned*)(Ln + f*256 + SWZ(f, hz*2)) = 0u;
        }
    }
    __syncthreads();   // B4

    int mt = w;

    if (mt < 7){
        bf16x8 bfr8[4];
        #pragma unroll
        for (int kc=0;kc<4;kc++)
            bfr8[kc] = *(const bf16x8*)(mextT + (128+(l15&1))*H_ + kc*32 + l4*8);
        f32x4 acc = {0.f,0.f,0.f,0.f};
        #pragma unroll
        for (int kc=0;kc<4;kc++){
            bf16x8 a = *(const bf16x8*)(Ln + (mt*16+l15)*256 + SWZ(mt*16+l15, (kc*32+l4*8)*2));
            acc = mfma16(a, bfr8[kc], acc);
        }
        if (l15==0){
            #pragma unroll
            for (int j=0;j<4;j++) sAlpha[mt*16+l4*4+j] = acc[j];
        }
        if (l15==1){
            #pragma unroll
            for (int j=0;j<4;j++) sBeta[mt*16+l4*4+j] = acc[j];
        }
    }
    __syncthreads();   // B5

    const float cc = cconst[0];
    unsigned long long uexB[3];
    if (mt < 7){
        bf16x8 afxi[4];
        #pragma unroll
        for (int kc=0;kc<4;kc++)
            afxi[kc] = *(const bf16x8*)(Ln + (mt*16+l15)*256 + SWZ(mt*16+l15, (kc*32+l4*8)*2));
        f32x4 sc[7];
        #pragma unroll
        for (int gt=0; gt<7; gt++) sc[gt] = (f32x4){0.f,0.f,0.f,0.f};
        #pragma unroll 1
        for (int p=0; p<2; p++){
            #pragma unroll 2
            for (int nt4=0; nt4<4; nt4++){
                int nt = p*4 + nt4;
                bf16x8 bw[4];
                #pragma unroll
                for (int kc=0;kc<4;kc++)
                    bw[kc] = *(const bf16x8*)(Lm + (nt*16+l15)*256 + SWZ(nt*16+l15, (kc*32+l4*8)*2));
                f32x4 d = {0.f,0.f,0.f,0.f};
                #pragma unroll
                for (int kc=0;kc<4;kc++) d = mfma16(bw[kc], afxi[kc], d);   // D[n][f]
                *(unsigned long long*)(&sP[l15][nt4*16 + l4*4]) = pack4_(d[0],d[1],d[2],d[3]);
            }
            bf16x8 afs0 = *(const bf16x8*)&sP[l15][l4*8];
            bf16x8 afs1 = *(const bf16x8*)&sP[l15][32+l4*8];
            #pragma unroll
            for (int gt=0; gt<7; gt++){
                int r = gt*16+l15;
                bf16x8 b0 = *(const bf16x8*)(Ln + r*256 + SWZ(r, (p*64 + l4*8)*2));
                bf16x8 b1 = *(const bf16x8*)(Ln + r*256 + SWZ(r, (p*64 + 32 + l4*8)*2));
                sc[gt] = mfma16(b0, afs0, sc[gt]);   // D[g][f]
                sc[gt] = mfma16(b1, afs1, sc[gt]);
            }
        }
        float aj = sAlpha[mt*16+l15];
        float rs = 0.f;
        #pragma unroll
        for (int gt=0; gt<7; gt++){
            f32x4 bt4 = *(const f32x4*)&sBeta[gt*16+l4*4];
            float e[4];
            #pragma unroll
            for (int j=0;j<4;j++){
                int g = gt*16 + l4*4 + j;
                float val = sc[gt][j] + aj + bt4[j] + cc;
                e[j] = (g<F_) ? __expf(sigmoidf_(val)) : 0.f;
                rs += e[j];
            }
            if (gt < 4)
                *(unsigned long long*)(&sP[l15][gt*16 + l4*4]) = pack4_(e[0],e[1],e[2],e[3]);
            else
                uexB[gt-4] = pack4_(e[0],e[1],e[2],e[3]);
        }
        rs += __shfl_xor(rs, 16, 64);
        rs += __shfl_xor(rs, 32, 64);
        if (l4 == 0) sInv[w*16 + l15] = 1.f/rs;
    } else {
        int h = lane;
        float a0=0.f, a1=0.f;
        #pragma unroll 4
        for (int f=0; f<F_; ++f){
            float awf = sAw[f];
            a0 += awf * (float)*(const bf16*)(Ln + f*256 + SWZ(f, h*2));
            a1 += awf * (float)*(const bf16*)(Ln + f*256 + SWZ(f, (h+64)*2));
        }
        xtb[(size_t)b*H_ + h]      = (bf16)(a0 * sNorm[h]);
        xtb[(size_t)b*H_ + h + 64] = (bf16)(a1 * sNorm[h+64]);
    }

    unsigned long long vpku[7];
    #pragma unroll
    for (int gt=0; gt<7; gt++){
        f32x4 acc = {0.f,0.f,0.f,0.f};
        #pragma unroll
        for (int kc=0;kc<4;kc++){
            int r = gt*16+l15;
            bf16x8 a = *(const bf16x8*)(Ln + r*256 + SWZ(r, (kc*32+l4*8)*2));
            acc = mfma16(a, awv[kc], acc);
        }
        vpku[gt] = pack4_(acc[0]+vbr, acc[1]+vbr, acc[2]+vbr, acc[3]+vbr);
    }
    __syncthreads();   // B6

    {
        int hrow = w*16 + l15;
        #pragma unroll
        for (int gt=0; gt<7; gt++)
            *(unsigned long long*)(Lm + hrow*256 + SWZ(hrow, gt*32 + l4*8)) = vpku[gt];
    }
    __syncthreads();   // B7

    if (mt < 7){
        bf16x8 ap0 = *(const bf16x8*)&sP[l15][l4*8];
        bf16x8 ap1 = *(const bf16x8*)&sP[l15][32+l4*8];
        f32x4 acc8[8];
        #pragma unroll
        for (int ht=0;ht<8;ht++) acc8[ht] = (f32x4){0.f,0.f,0.f,0.f};
        #pragma unroll
        for (int ht=0; ht<8; ht++){
            int r = ht*16+l15;
            bf16x8 bv0 = *(const bf16x8*)(Lm + r*256 + SWZ(r, (l4*8)*2));
            bf16x8 bv1 = *(const bf16x8*)(Lm + r*256 + SWZ(r, (32+l4*8)*2));
            acc8[ht] = mfma16(ap0, bv0, acc8[ht]);
            acc8[ht] = mfma16(ap1, bv1, acc8[ht]);
        }
        #pragma unroll
        for (int gt=4; gt<7; gt++)
            *(unsigned long long*)(&sP[l15][(gt-4)*16 + l4*4]) = uexB[gt-4];
        *(unsigned long long*)(&sP[l15][48 + l4*4]) = 0ull;
        bf16x8 ap2 = *(const bf16x8*)&sP[l15][l4*8];
        bf16x8 ap3 = *(const bf16x8*)&sP[l15][32+l4*8];
        #pragma unroll
        for (int ht=0; ht<8; ht++){
            int r = ht*16+l15;
            int c2 = 64+l4*8;
            int c3 = 96+l4*8;  if (c3 >= 112) c3 = 96;
            bf16x8 bv2 = *(const bf16x8*)(Lm + r*256 + SWZ(r, c2*2));
            bf16x8 bv3 = *(const bf16x8*)(Lm + r*256 + SWZ(r, c3*2));
            acc8[ht] = mfma16(ap2, bv2, acc8[ht]);
            acc8[ht] = mfma16(ap3, bv3, acc8[ht]);
        }
        float fs[4];
        #pragma unroll
        for (int j=0;j<4;j++) fs[j] = sInv[w*16 + l4*4 + j] * FP8SC;
        #pragma unroll
        for (int ht=0; ht<8; ht++){
            unsigned u = cvtfp8x4_(acc8[ht][0]*fs[0], acc8[ht][1]*fs[1], acc8[ht][2]*fs[2], acc8[ht][3]*fs[3]);
            if (mt < 6){
                *(unsigned*)(xxb + (size_t)b*KC_ + (mt*8+ht)*256 + lane*4) = u;
            } else if (l4 == 0){
                *(unsigned*)(xxb + (size_t)b*KC_ + 12288 + ht*64 + l15*4) = u;
            }
        }
    }
}

// ---------------- fp8 split-K GEMM: 128x256 tile, 512 thr, bf16 partials ----------------
// grid (N/256, M/128, SPLIT) = (2,64,4) = 512 blocks, 2/CU
__global__ __launch_bounds__(512,2) void k_gemm_fp8(const unsigned char* __restrict__ A,
        const unsigned char* __restrict__ Bt, bf16* __restrict__ part, int M, int N, int K, int KS)
{
    __shared__ unsigned char sA[128][144];
    __shared__ unsigned char sB[256][144];
    int tid=threadIdx.x, w=tid>>6, lane=tid&63, l15=lane&15, l4=lane>>4;
    int m0 = blockIdx.y*128, n0 = blockIdx.x*256;
    int kbeg = blockIdx.z*KS, kend = kbeg + KS;
    int wr = w>>2, wc = w&3;
    f32x4 acc[4][4];
    #pragma unroll
    for(int mi=0;mi<4;mi++)
        #pragma unroll
        for(int ni=0;ni<4;ni++) acc[mi][ni] = (f32x4){0.f,0.f,0.f,0.f};

    for (int k0=kbeg; k0<kend; k0+=128){
        __syncthreads();
        #pragma unroll
        for (int t2=0;t2<2;t2++){
            int t = tid + t2*512;
            int row=t>>3, col=(t&7)*16;
            *(u32x4*)&sA[row][col] = *(const u32x4*)(A + (size_t)(m0+row)*K + k0 + col);
        }
        #pragma unroll
        for (int t4=0;t4<4;t4++){
            int t = tid + t4*512;
            int row=t>>3, col=(t&7)*16;
            *(u32x4*)&sB[row][col] = *(const u32x4*)(Bt + (size_t)(n0+row)*K + k0 + col);
        }
        __syncthreads();
        #pragma unroll
        for(int ks=0;ks<4;ks++){
            long af[4], bfr[4];
            #pragma unroll
            for(int mi=0;mi<4;mi++) af[mi] = *(const long*)&sA[wr*64+mi*16+l15][ks*32+l4*8];
            #pragma unroll
            for(int ni=0;ni<4;ni++) bfr[ni] = *(const long*)&sB[wc*64+ni*16+l15][ks*32+l4*8];
            #pragma unroll
            for(int mi=0;mi<4;mi++)
                #pragma unroll
                for(int ni=0;ni<4;ni++)
                    acc[mi][ni] = mfma8(af[mi], bfr[ni], acc[mi][ni]);
        }
    }
    bf16* pz = part + (size_t)blockIdx.z*M*N;
    #pragma unroll
    for(int mi=0;mi<4;mi++)
        #pragma unroll
        for(int ni=0;ni<4;ni++){
            int col = n0 + wc*64 + ni*16 + l15;
            #pragma unroll
            for(int j=0;j<4;j++){
                int row = m0 + wr*64 + mi*16 + l4*4 + j;
                pz[(size_t)row*N + col] = (bf16)acc[mi][ni][j];
            }
        }
}

// reduce SPLIT bf16 partials + bias + ELU -> bf16
__global__ void k_c1fin(const bf16* __restrict__ part, const float* __restrict__ bias,
                        bf16* __restrict__ out){
    const size_t MN = (size_t)B_*512;
    size_t e0 = ((size_t)blockIdx.x*256 + threadIdx.x)*4;
    bf16x4 p0 = *(const bf16x4*)(part + e0);
    bf16x4 p1 = *(const bf16x4*)(part + MN + e0);
    bf16x4 p2 = *(const bf16x4*)(part + 2*MN + e0);
    bf16x4 p3 = *(const bf16x4*)(part + 3*MN + e0);
    f32x4 bb = *(const f32x4*)(bias + (e0 & 511));
    const float ds = 1.0f/(FP8SC*FP8SC);
    float s0 = ((float)p0[0]+(float)p1[0]+(float)p2[0]+(float)p3[0])*ds + bb[0];
    float s1 = ((float)p0[1]+(float)p1[1]+(float)p2[1]+(float)p3[1])*ds + bb[1];
    float s2 = ((float)p0[2]+(float)p1[2]+(float)p2[2]+(float)p3[2])*ds + bb[2];
    float s3 = ((float)p0[3]+(float)p1[3]+(float)p2[3]+(float)p3[3])*ds + bb[3];
    unsigned long long u = pack4_(eluf_(s0), eluf_(s1), eluf_(s2), eluf_(s3));
    *(unsigned long long*)(out + e0) = u;
}

// ---------------- generic tiled GEMM (c2, c3) ----------------
template<int BN, bool ELU>
__global__ __launch_bounds__(256,2) void k_gemm(const bf16* __restrict__ A, const bf16* __restrict__ Bt,
        const float* __restrict__ bias, bf16* __restrict__ out, int M, int N, int K)
{
    __shared__ bf16 sAt[128][72];
    __shared__ bf16 sBt[BN][72];
    int tid=threadIdx.x, w=tid>>6, lane=tid&63, l15=lane&15, l4=lane>>4;
    int m0 = blockIdx.y*128, n0 = blockIdx.x*BN;
    constexpr int MI = (BN==128)?4:2;
    constexpr int NI = (BN==128)?4:BN/16;
    int wr = (BN==128)? (w>>1) : w;
    int wc = (BN==128)? (w&1) : 0;
    f32x4 acc[MI][NI];
    #pragma unroll
    for(int mi=0;mi<MI;mi++)
        #pragma unroll
        for(int ni=0;ni<NI;ni++) acc[mi][ni] = (f32x4){0.f,0.f,0.f,0.f};

    for (int k0=0; k0<K; k0+=64){
        __syncthreads();
        for (int t=tid; t<128*8; t+=256){
            int row=t>>3, col=(t&7)*8;
            *(bf16x8*)&sAt[row][col] = *(const bf16x8*)(A + (size_t)(m0+row)*K + k0 + col);
        }
        for (int t=tid; t<BN*8; t+=256){
            int row=t>>3, col=(t&7)*8;
            *(bf16x8*)&sBt[row][col] = *(const bf16x8*)(Bt + (size_t)(n0+row)*K + k0 + col);
        }
        __syncthreads();
        #pragma unroll
        for(int ks=0;ks<2;ks++){
            bf16x8 af[MI], bfr[NI];
            #pragma unroll
            for(int mi=0;mi<MI;mi++) af[mi] = *(const bf16x8*)&sAt[wr*(MI*16)+mi*16+l15][ks*32+l4*8];
            #pragma unroll
            for(int ni=0;ni<NI;ni++) bfr[ni] = *(const bf16x8*)&sBt[wc*64+ni*16+l15][ks*32+l4*8];
            #pragma unroll
            for(int mi=0;mi<MI;mi++)
                #pragma unroll
                for(int ni=0;ni<NI;ni++)
                    acc[mi][ni] = mfma16(af[mi], bfr[ni], acc[mi][ni]);
        }
    }
    #pragma unroll
    for(int mi=0;mi<MI;mi++)
        #pragma unroll
        for(int ni=0;ni<NI;ni++){
            int col = n0 + wc*64 + ni*16 + l15;
            float bc = bias[col];
            #pragma unroll
            for(int j=0;j<4;j++){
                int row = m0 + wr*(MI*16) + mi*16 + l4*4 + j;
                float v = acc[mi][ni][j] + bc;
                if (ELU) v = eluf_(v);
                out[(size_t)row*N + col] = (bf16)v;
            }
        }
}

// ---------------- merged tails ----------------
__global__ __launch_bounds__(256,2) void k_tails(const bf16* __restrict__ c3o,
    const float* __restrict__ c4w, const float* __restrict__ c4b,
    const float* __restrict__ c5w, const float* __restrict__ c5b,
    const float* __restrict__ clw, const float* __restrict__ clb,
    const float* __restrict__ ctw, const float* __restrict__ ctb,
    const bf16* __restrict__ xtb,
    const float* __restrict__ u1w, const float* __restrict__ u1b,
    const float* __restrict__ u2w, const float* __restrict__ u2b,
    const float* __restrict__ u3w, const float* __restrict__ u3b,
    const float* __restrict__ u4w, const float* __restrict__ u4b,
    const float* __restrict__ tlw, const float* __restrict__ tlb,
    const float* __restrict__ utw, const float* __restrict__ utb, float* __restrict__ outp)
{
    __shared__ char A[58880];
    int tid = threadIdx.x, blk = blockIdx.x;
    int r0 = (blk>>1)*32;
    if ((blk & 1) == 0){
        float (*sA)[260] = (float(*)[260])A;
        float (*sB)[132] = (float(*)[132])(A + 33280);
        float (*sC)[68]  = (float(*)[68])(A + 50176);
        for (int v=tid; v<32*64; v+=256){
            int r=v>>6, c=(v&63)*4;
            bf16x4 x = *(const bf16x4*)(c3o + (size_t)(r0+r)*256 + c);
            sA[r][c]=(float)x[0]; sA[r][c+1]=(float)x[1]; sA[r][c+2]=(float)x[2]; sA[r][c+3]=(float)x[3];
        }
        __syncthreads();
        {
            int j = tid&127, rb = tid>>7;
            float acc[16];
            #pragma unroll
            for (int i=0;i<16;i++) acc[i]=c4b[j];
            #pragma unroll 4
            for (int h=0;h<256;h++){
                float wv = c4w[h*128+j];
                #pragma unroll
                for (int i=0;i<16;i++) acc[i] += sA[2*i+rb][h]*wv;
            }
            #pragma unroll
            for (int i=0;i<16;i++) sB[2*i+rb][j] = eluf_(acc[i]);
        }
        __syncthreads();
        {
            int j = tid&63, rb = tid>>6;
            float acc[8];
            #pragma unroll
            for (int i=0;i<8;i++) acc[i]=c5b[j];
            #pragma unroll 4
            for (int h=0;h<128;h++){
                float wv = c5w[h*64+j];
                #pragma unroll
                for (int i=0;i<8;i++) acc[i] += sB[4*i+rb][h]*wv;
            }
            #pragma unroll
            for (int i=0;i<8;i++) sC[4*i+rb][j] = eluf_(acc[i]);
        }
        __syncthreads();
        if (tid < 32){
            float r1 = clb[0], r2 = ctb[0];
            #pragma unroll 8
            for (int k=0;k<64;k++){ float v = sC[tid][k]; r1 += v*clw[k]; r2 += v*ctw[k]; }
            int row = r0 + tid;
            outp[row] = r1;
            outp[B_ + row] = sigmoidf_(r1);
            outp[(size_t)2*B_ + row] = r2;
        }
    } else {
        float (*sA)[132] = (float(*)[132])A;
        float (*sB)[132] = (float(*)[132])(A + 16896);
        float (*sC)[68]  = (float(*)[68])(A + 33792);
        float (*sD)[36]  = (float(*)[36])(A + 42496);
        float (*sE)[20]  = (float(*)[20])(A + 47104);
        for (int v=tid; v<32*32; v+=256){
            int r=v>>5, c=(v&31)*4;
            bf16x4 x = *(const bf16x4*)(xtb + (size_t)(r0+r)*128 + c);
            sA[r][c]=(float)x[0]; sA[r][c+1]=(float)x[1]; sA[r][c+2]=(float)x[2]; sA[r][c+3]=(float)x[3];
        }
        __syncthreads();
        {
            int j = tid&127, rb = tid>>7;
            float acc[16];
            #pragma unroll
            for (int i=0;i<16;i++) acc[i]=u1b[j];
            #pragma unroll 4
            for (int h=0;h<128;h++){
                float wv = u1w[h*128+j];
                #pragma unroll
                for (int i=0;i<16;i++) acc[i] += sA[2*i+rb][h]*wv;
            }
            #pragma unroll
            for (int i=0;i<16;i++) sB[2*i+rb][j] = eluf_(acc[i]);
        }
        __syncthreads();
        {
            int j = tid&63, rb = tid>>6;
            float acc[8];
            #pragma unroll
            for (int i=0;i<8;i++) acc[i]=u2b[j];
            #pragma unroll 4
            for (int h=0;h<128;h++){
                float wv = u2w[h*64+j];
                #pragma unroll
                for (int i=0;i<8;i++) acc[i] += sB[4*i+rb][h]*wv;
            }
            #pragma unroll
            for (int i=0;i<8;i++) sC[4*i+rb][j] = eluf_(acc[i]);
        }
        __syncthreads();
        {
            int j = tid&31, rb = tid>>5;
            float acc[4];
            #pragma unroll
            for (int i=0;i<4;i++) acc[i]=u3b[j];
            #pragma unroll 4
            for (int h=0;h<64;h++){
                float wv = u3w[h*32+j];
                #pragma unroll
                for (int i=0;i<4;i++) acc[i] += sC[8*i+rb][h]*wv;
            }
            #pragma unroll
            for (int i=0;i<4;i++) sD[8*i+rb][j] = eluf_(acc[i]);
        }
        __syncthreads();
        {
            int j = tid&15, rb = tid>>4;
            float acc0=u4b[j], acc1=u4b[j];
            #pragma unroll 4
            for (int h=0;h<32;h++){
                float wv = u4w[h*16+j];
                acc0 += sD[rb][h]*wv;
                acc1 += sD[16+rb][h]*wv;
            }
            sE[rb][j] = eluf_(acc0);
            sE[16+rb][j] = eluf_(acc1);
        }
        __syncthreads();
        if (tid < 32){
            float r1 = tlb[0], r2 = utb[0];
            #pragma unroll
            for (int k=0;k<16;k++){ float v = sE[tid][k]; r1 += v*tlw[k]; r2 += v*utw[k]; }
            int row = r0 + tid;
            outp[(size_t)3*B_ + row] = r1;
            outp[(size_t)4*B_ + row] = sigmoidf_(r1);
            outp[(size_t)5*B_ + row] = r2;
        }
    }
}

extern "C" void kernel_launch(void* const* d_in, const int* in_sizes, int n_in,
                              void* d_out, int out_size, void* d_ws, size_t ws_size,
                              hipStream_t stream) {
    const float* feat=(const float*)d_in[0];
    const float* emb =(const float*)d_in[2];
    const float* t_w =(const float*)d_in[3]; const float* t_b=(const float*)d_in[4];
    const float* qw  =(const float*)d_in[5]; const float* qb =(const float*)d_in[6];
    const float* kw  =(const float*)d_in[7]; const float* kb =(const float*)d_in[8];
    const float* vw  =(const float*)d_in[9]; const float* vb =(const float*)d_in[10];
    const float* a1w =(const float*)d_in[11];
    const float* a2w =(const float*)d_in[12]; const float* a2b=(const float*)d_in[13];
    const float* a3w =(const float*)d_in[14];
    const float* c1w =(const float*)d_in[15]; const float* c1b=(const float*)d_in[16];
    const float* c2w =(const float*)d_in[17]; const float* c2b=(const float*)d_in[18];
    const float* c3w =(const float*)d_in[19]; const float* c3b=(const float*)d_in[20];
    const float* c4w =(const float*)d_in[21]; const float* c4b=(const float*)d_in[22];
    const float* c5w =(const float*)d_in[23]; const float* c5b=(const float*)d_in[24];
    const float* clw =(const float*)d_in[25]; const float* clb=(const float*)d_in[26];
    const float* ctw =(const float*)d_in[27]; const float* ctb=(const float*)d_in[28];
    const float* u1w =(const float*)d_in[29]; const float* u1b=(const float*)d_in[30];
    const float* u2w =(const float*)d_in[31]; const float* u2b=(const float*)d_in[32];
    const float* u3w =(const float*)d_in[33]; const float* u3b=(const float*)d_in[34];
    const float* u4w =(const float*)d_in[35]; const float* u4b=(const float*)d_in[36];
    const float* tlw =(const float*)d_in[37]; const float* tlb=(const float*)d_in[38];
    const float* utw =(const float*)d_in[39]; const float* utb=(const float*)d_in[40];
    float* outp = (float*)d_out;

    char* ws = (char*)d_ws;
    size_t off = 0;
    auto alloc = [&](size_t bytes)->char*{ char* p = ws + off; off += (bytes + 255) & ~(size_t)255; return p; };
    unsigned char* xxb = (unsigned char*)alloc((size_t)B_*KC_);
    bf16* part   = (bf16*)alloc((size_t)SPLIT_*B_*512*2);
    float* attg  = (float*)alloc((size_t)B_*FP*4);
    bf16* xtb    = (bf16*)alloc((size_t)B_*128*2);
    bf16* cbuf1  = (bf16*)alloc((size_t)B_*512*2);
    bf16* mextT  = (bf16*)alloc(144*128*2);
    bf16* wvT    = (bf16*)alloc(128*128*2);
    bf16* wa2t   = (bf16*)alloc(128*128*2);
    unsigned char* c1wtk8 = (unsigned char*)alloc((size_t)512*KC_);
    bf16* c2wt   = (bf16*)alloc((size_t)512*512*2);
    bf16* c3wt   = (bf16*)alloc((size_t)512*256*2);
    float* sigt  = (float*)alloc(128*4);
    float* cconst= (float*)alloc(4);
    bf16* cbuf2 = (bf16*)(xxb);
    bf16* cbuf3 = (bf16*)(xxb + (16u<<20));
    (void)ws_size; (void)in_sizes; (void)n_in; (void)out_size;

    k_prep_all<<<426,256,0,stream>>>(qw,qb,kw,kb,t_w,t_b,a1w, vw, a2w, c2w, c3w,
                                     mextT, sigt, cconst, wvT, wa2t, c2wt, c3wt);

    k_gk<<<13568,256,0,stream>>>(c1w, c1wtk8, feat, emb, wa2t, a2b, a3w, sigt, attg);

    k_attn2<<<B_,512,0,stream>>>(feat,emb,mextT,wvT,vb,cconst,attg, xxb, xtb);

    k_gemm_fp8<<<dim3(2,64,SPLIT_),512,0,stream>>>(xxb, c1wtk8, part, B_,512,KC_, KC_/SPLIT_);
    k_c1fin<<<4096,256,0,stream>>>(part, c1b, cbuf1);

    k_gemm<128,true><<<dim3(4,64),256,0,stream>>>(cbuf1, c2wt, c2b, cbuf2, B_,512,512);
    k_gemm<64,true><<<dim3(4,64),256,0,stream>>>(cbuf2, c3wt, c3b, cbuf3, B_,256,512);

    k_tails<<<512,256,0,stream>>>(cbuf3,c4w,c4b,c5w,c5b,clw,clb,ctw,ctb,
                                  xtb,u1w,u1b,u2w,u2b,u3w,u3b,u4w,u4b,tlw,tlb,utw,utb,outp);
}

// Round 19
// 620.762 us; speedup vs baseline: 1.2546x; 1.0181x over previous
//
#include <hip/hip_runtime.h>
#include <hip/hip_bf16.h>

typedef __bf16 bf16;
typedef __bf16 bf16x8 __attribute__((ext_vector_type(8)));
typedef __bf16 bf16x4 __attribute__((ext_vector_type(4)));
typedef float f32x4 __attribute__((ext_vector_type(4)));
typedef unsigned u32x4 __attribute__((ext_vector_type(4)));

#define DEVI static __device__ __forceinline__

DEVI float sigmoidf_(float x){ return 1.0f/(1.0f+__expf(-x)); }
DEVI float eluf_(float x){ return x>0.f ? x : (__expf(x)-1.f); }
DEVI f32x4 mfma16(bf16x8 a, bf16x8 b, f32x4 c){ return __builtin_amdgcn_mfma_f32_16x16x32_bf16(a,b,c,0,0,0); }
DEVI f32x4 mfma8(long a, long b, f32x4 c){ return __builtin_amdgcn_mfma_f32_16x16x32_fp8_fp8(a,b,c,0,0,0); }
DEVI unsigned pack2_(float a, float b){
    union { bf16 v[2]; unsigned u; } t; t.v[0]=(bf16)a; t.v[1]=(bf16)b; return t.u;
}
DEVI unsigned long long pack4_(float a, float b, float c, float d){
    union { bf16 v[4]; unsigned long long u; } t;
    t.v[0]=(bf16)a; t.v[1]=(bf16)b; t.v[2]=(bf16)c; t.v[3]=(bf16)d; return t.u;
}
DEVI unsigned cvtfp8x4_(float a, float b, float c, float d){
    int v = __builtin_amdgcn_cvt_pk_fp8_f32(a, b, 0, false);
    v = __builtin_amdgcn_cvt_pk_fp8_f32(c, d, v, true);
    return (unsigned)v;
}
// async global->LDS, 16 B per lane (lds dest wave-uniform base + lane*16)
DEVI void gld16_(const void* g, void* l){
    __builtin_amdgcn_global_load_lds((const __attribute__((address_space(1))) void*)g,
                                     (__attribute__((address_space(3))) void*)l, 16, 0, 0);
}

#define B_ 8192
#define F_ 100
#define FP 112
#define H_ 128
#define KC_ 12800
#define SPLIT_ 4
#define FP8SC 16.0f

#define SWZ(r,bc) ((bc) ^ (((r)&7)<<4))
// fp8-GEMM operand bake: permute k within each 128-B chunk by row parity
DEVI int swzk_(int row, int k){ return (k & ~127) | ((k & 127) ^ ((row&7)<<4)); }

// ---------------- mega weight prep ----------------
DEVI void dotrans_(float (*t)[33], const float* in, bf16* out, int R, int C, int bx, int by, int tid){
    int c0 = bx*32, r0 = by*32;
    int tc = tid & 31, tr = tid >> 5;
    #pragma unroll
    for (int i=0;i<4;i++){
        int r = tr + i*8;
        t[r][tc] = in[(size_t)(r0+r)*C + c0 + tc];
    }
    __syncthreads();
    #pragma unroll
    for (int i=0;i<4;i++){
        int ro = tr + i*8;
        out[(size_t)(c0+ro)*R + r0 + tc] = (bf16)t[tc][ro];
    }
}

__global__ void k_prep_all(const float* __restrict__ qw, const float* __restrict__ qb,
                           const float* __restrict__ kw, const float* __restrict__ kb,
                           const float* __restrict__ tw, const float* __restrict__ tb,
                           const float* __restrict__ a1w, const float* __restrict__ vw,
                           const float* __restrict__ a2w, const float* __restrict__ c2w,
                           const float* __restrict__ c3w,
                           bf16* __restrict__ mextT, float* __restrict__ sigt, float* __restrict__ cconst,
                           bf16* __restrict__ wvT, bf16* __restrict__ wa2t,
                           bf16* __restrict__ c2wt, bf16* __restrict__ c3wt){
    __shared__ float t[32][33];
    const float rsc = 0.08838834764831845f;
    int blk = blockIdx.x, tid = threadIdx.x;
    if (blk < 9){
        #pragma unroll 1
        for (int e=0; e<8; ++e){
            int idx = e*256 + tid;
            int n = blk*16 + (idx>>7), h = idx&127;
            float acc = 0.f;
            if (n < 128){
                for (int d=0; d<128; ++d) acc += qw[h*128+d]*kw[n*128+d];
            } else if (n == 128){
                for (int d=0; d<128; ++d) acc += qw[h*128+d]*kb[d];
            } else if (n == 129){
                for (int d=0; d<128; ++d) acc += kw[h*128+d]*qb[d];
            }
            mextT[n*128+h] = (bf16)(acc*rsc);
        }
    } else if (blk == 9){
        if (tid < 128){
            float acc = 0.f;
            for (int h=0; h<128; ++h) acc += (tw[h]+tb[h]) * a1w[h*128+tid];
            sigt[tid] = sigmoidf_(acc);
        } else if (tid == 128){
            float acc = 0.f;
            for (int d=0; d<128; ++d) acc += qb[d]*kb[d];
            cconst[0] = acc*rsc;
        }
    } else if (blk < 26){
        int i = blk-10; dotrans_(t, vw, wvT, 128,128, i&3, i>>2, tid);
    } else if (blk < 42){
        int i = blk-26; dotrans_(t, a2w, wa2t, 128,128, i&3, i>>2, tid);
    } else if (blk < 298){
        int i = blk-42; dotrans_(t, c2w, c2wt, 512,512, i&15, i>>4, tid);
    } else {
        int i = blk-298; dotrans_(t, c3w, c3wt, 512,256, i&7, i>>3, tid);
    }
}

// compact kappa: bijection on [0,12800)
DEVI int kappa_(int k){
    int f = k>>7, h = k&127;
    if (f < 96)
        return (((f>>4)<<3) | (h>>4))*256 + ((f&15)>>2)*64 + (h&15)*4 + (f&3);
    else
        return 12288 + (h>>4)*64 + (h&15)*4 + (f&3);
}

// ---------------- merged: c1w kappa-fp8 prep (blocks 0..6399) + gatt GEMM (6400..13567) ----------------
__global__ __launch_bounds__(256,2) void k_gk(
    const float* __restrict__ c1w, unsigned char* __restrict__ c1wtk8,
    const float* __restrict__ feat, const float* __restrict__ emb,
    const bf16* __restrict__ wa2t, const float* __restrict__ a2b,
    const float* __restrict__ a3w, const float* __restrict__ sigt,
    float* __restrict__ attg)
{
    __shared__ char A[37888];
    int blk = blockIdx.x, tid = threadIdx.x;
    if (blk < 6400){
        float (*t)[33] = (float(*)[33])A;
        const int C = 512;
        int c0 = (blk&15)*32, r0 = (blk>>4)*32;
        int tc = tid & 31, tr = tid >> 5;
        #pragma unroll
        for (int i=0;i<4;i++){
            int r = tr + i*8;
            t[r][tc] = c1w[(size_t)(r0+r)*C + c0 + tc];
        }
        __syncthreads();
        #pragma unroll
        for (int i=0;i<4;i++){
            int ro = tr + i*8;
            float x = t[tc][ro]*FP8SC;
            int v = __builtin_amdgcn_cvt_pk_fp8_f32(x, x, 0, false);
            int n = c0+ro;
            c1wtk8[(size_t)n*KC_ + swzk_(n, kappa_(r0+tc))] = (unsigned char)v;
        }
        return;
    }
    bf16 (*sAt)[72] = (bf16(*)[72])A;
    bf16 (*sBt)[72] = (bf16(*)[72])(A + 18432);
    float (*sRed)[128] = (float(*)[128])(A + 36864);
    int w=tid>>6, lane=tid&63, l15=lane&15, l4=lane>>4;
    int m0 = (blk-6400)*128;
    int wr = w>>1, wc = w&1;
    f32x4 acc[4][4];
    #pragma unroll
    for(int mi=0;mi<4;mi++)
        #pragma unroll
        for(int ni=0;ni<4;ni++) acc[mi][ni] = (f32x4){0.f,0.f,0.f,0.f};

    #pragma unroll 1
    for (int k0=0; k0<128; k0+=64){
        __syncthreads();
        #pragma unroll
        for (int t4=0; t4<4; t4++){
            int t = tid + t4*256;
            int row=t>>3, col=(t&7)*8;
            int gr = m0+row;
            int bb = gr/112, ff = gr - bb*112;
            bf16x8 o;
            if (ff < F_){
                float fv = feat[(size_t)bb*F_ + ff];
                const float* ep = emb + ff*H_ + k0 + col;
                f32x4 e0 = *(const f32x4*)ep;
                f32x4 e1 = *(const f32x4*)(ep+4);
                o[0]=(bf16)(fv*e0[0]); o[1]=(bf16)(fv*e0[1]); o[2]=(bf16)(fv*e0[2]); o[3]=(bf16)(fv*e0[3]);
                o[4]=(bf16)(fv*e1[0]); o[5]=(bf16)(fv*e1[1]); o[6]=(bf16)(fv*e1[2]); o[7]=(bf16)(fv*e1[3]);
            } else {
                #pragma unroll
                for (int e=0;e<8;e++) o[e]=(bf16)0.f;
            }
            *(bf16x8*)&sAt[row][col] = o;
            *(bf16x8*)&sBt[row][col] = *(const bf16x8*)(wa2t + row*H_ + k0 + col);
        }
        __syncthreads();
        #pragma unroll
        for(int ks=0;ks<2;ks++){
            bf16x8 af[4], bfr[4];
            #pragma unroll
            for(int mi=0;mi<4;mi++) af[mi] = *(const bf16x8*)&sAt[wr*64+mi*16+l15][ks*32+l4*8];
            #pragma unroll
            for(int ni=0;ni<4;ni++) bfr[ni] = *(const bf16x8*)&sBt[wc*64+ni*16+l15][ks*32+l4*8];
            #pragma unroll
            for(int mi=0;mi<4;mi++)
                #pragma unroll
                for(int ni=0;ni<4;ni++)
                    acc[mi][ni] = mfma16(af[mi], bfr[ni], acc[mi][ni]);
        }
    }
    float sg[4], ab[4], a3[4];
    #pragma unroll
    for (int ni=0;ni<4;ni++){
        int n = wc*64 + ni*16 + l15;
        sg[ni]=sigt[n]; ab[ni]=a2b[n]; a3[ni]=a3w[n];
    }
    #pragma unroll
    for (int mi=0;mi<4;mi++){
        float sj[4] = {0.f,0.f,0.f,0.f};
        #pragma unroll
        for (int ni=0;ni<4;ni++){
            #pragma unroll
            for (int j=0;j<4;j++){
                float u = sigmoidf_(acc[mi][ni][j] + ab[ni]);
                float t = sg[ni] + u;
                t = t>0.f ? t : 0.f;
                sj[j] += t*a3[ni];
            }
        }
        #pragma unroll
        for (int j=0;j<4;j++){
            float v = sj[j];
            #pragma unroll
            for (int m=1;m<16;m<<=1) v += __shfl_xor(v,m,16);
            sj[j]=v;
        }
        if (l15==0){
            #pragma unroll
            for (int j=0;j<4;j++) sRed[wc][wr*64+mi*16+l4*4+j] = sj[j];
        }
    }
    __syncthreads();
    if (tid < 128) attg[(size_t)m0 + tid] = sRed[0][tid] + sRed[1][tid];
}

// ---------------- fused per-batch attention ----------------
__global__ __launch_bounds__(512,2) void k_attn2(
    const float* __restrict__ feat, const float* __restrict__ emb,
    const bf16* __restrict__ mextT, const bf16* __restrict__ wvT,
    const float* __restrict__ vb, const float* __restrict__ cconst,
    const float* __restrict__ attg,
    unsigned char* __restrict__ xxb, bf16* __restrict__ xtb)
{
    __shared__ char L[81792];
    char* Lm = L;
    char* Ln = L + 32768;
    float* sFeat  = (float*)(L+61440);
    float* normP  = (float*)(L+62336);   // [8][128] f32
    float* sAw    = (float*)(L+77568);   // wave-7 sP slot
    float* sNorm  = (float*)(L+79872);
    float* sAlpha = (float*)(L+80384);
    float* sBeta  = (float*)(L+80832);
    float* sInv   = (float*)(L+81280);   // [8][16]

    int b = blockIdx.x;
    int tid = threadIdx.x, w = tid>>6, lane = tid&63;
    int l15 = lane&15, l4 = lane>>4;
    bf16 (*sP)[72] = (bf16(*)[72])(L + 61440 + w*2304);

    bf16x8 awv[4];
    #pragma unroll
    for (int kc=0;kc<4;kc++)
        awv[kc] = *(const bf16x8*)(wvT + (w*16+l15)*H_ + kc*32 + l4*8);
    float vbr = vb[w*16+l15];

    #pragma unroll 2
    for (int v = tid; v < 128*16; v += 512){
        int n = v >> 4, cg = (v & 15) * 8;
        *(u32x4*)(Lm + n*256 + SWZ(n, cg*2)) = *(const u32x4*)(mextT + n*128 + cg);
    }
    if (tid < FP) sFeat[tid] = (tid<F_) ? feat[(size_t)b*F_+tid] : 0.f;
    if (w==0){
        const float* ag = attg + (size_t)b*FP;
        float a0 = (lane<F_)? ag[lane] : -1e30f;
        float a1 = (lane+64<F_)? ag[lane+64] : -1e30f;
        float m = fmaxf(a0,a1);
        #pragma unroll
        for(int s=1;s<64;s<<=1) m = fmaxf(m, __shfl_xor(m,s,64));
        float e0 = (lane<F_)? __expf(a0-m):0.f;
        float e1 = (lane+64<F_)? __expf(a1-m):0.f;
        float s = e0+e1;
        #pragma unroll
        for(int t=1;t<64;t<<=1) s += __shfl_xor(s,t,64);
        float inv = 1.f/s;
        if (lane<FP) sAw[lane] = e0*inv;
        if (lane+64<FP) sAw[lane+64] = e1*inv;
    }
    __syncthreads();   // B1

    int hp = (tid&63)*2, gg = tid>>6;
    {
        float fa0=0.f, fa1=0.f;
        #pragma unroll 4
        for (int it=0; it<13; ++it){
            int f = gg + 8*it;
            if (f < F_){
                float2 e2 = *(const float2*)(emb + f*H_ + hp);
                float v0 = sFeat[f]*e2.x, v1 = sFeat[f]*e2.y;
                fa0 += v0*v0; fa1 += v1*v1;
            }
        }
        *(float2*)(normP + gg*128 + hp) = make_float2(fa0, fa1);
    }
    __syncthreads();   // B2
    if (tid < 128){
        float s = 0.f;
        #pragma unroll
        for (int g2=0; g2<8; ++g2) s += normP[g2*128 + tid];
        sNorm[tid] = sqrtf(s);
    }
    __syncthreads();   // B3

    {
        float rn0 = __builtin_amdgcn_rcpf(sNorm[hp]);
        float rn1 = __builtin_amdgcn_rcpf(sNorm[hp+1]);
        #pragma unroll 4
        for (int it=0; it<13; ++it){
            int f = gg + 8*it;
            if (f < F_){
                float2 e2 = *(const float2*)(emb + f*H_ + hp);
                *(unsigned*)(Ln + f*256 + SWZ(f, hp*2)) = pack2_(sFeat[f]*e2.x*rn0, sFeat[f]*e2.y*rn1);
            }
        }
        for (int z=tid; z<768; z+=512){
            int f = 100 + (z>>6), hz = (z&63)*2;
            *(unsigned*)(Ln + f*256 + SWZ(f, hz*2)) = 0u;
        }
    }
    __syncthreads();   // B4

    int mt = w;

    if (mt < 7){
        bf16x8 bfr8[4];
        #pragma unroll
        for (int kc=0;kc<4;kc++)
            bfr8[kc] = *(const bf16x8*)(mextT + (128+(l15&1))*H_ + kc*32 + l4*8);
        f32x4 acc = {0.f,0.f,0.f,0.f};
        #pragma unroll
        for (int kc=0;kc<4;kc++){
            bf16x8 a = *(const bf16x8*)(Ln + (mt*16+l15)*256 + SWZ(mt*16+l15, (kc*32+l4*8)*2));
            acc = mfma16(a, bfr8[kc], acc);
        }
        if (l15==0){
            #pragma unroll
            for (int j=0;j<4;j++) sAlpha[mt*16+l4*4+j] = acc[j];
        }
        if (l15==1){
            #pragma unroll
            for (int j=0;j<4;j++) sBeta[mt*16+l4*4+j] = acc[j];
        }
    }
    __syncthreads();   // B5

    const float cc = cconst[0];
    unsigned long long uexB[3];
    if (mt < 7){
        bf16x8 afxi[4];
        #pragma unroll
        for (int kc=0;kc<4;kc++)
            afxi[kc] = *(const bf16x8*)(Ln + (mt*16+l15)*256 + SWZ(mt*16+l15, (kc*32+l4*8)*2));
        f32x4 sc[7];
        #pragma unroll
        for (int gt=0; gt<7; gt++) sc[gt] = (f32x4){0.f,0.f,0.f,0.f};
        #pragma unroll 1
        for (int p=0; p<2; p++){
            #pragma unroll 2
            for (int nt4=0; nt4<4; nt4++){
                int nt = p*4 + nt4;
                bf16x8 bw[4];
                #pragma unroll
                for (int kc=0;kc<4;kc++)
                    bw[kc] = *(const bf16x8*)(Lm + (nt*16+l15)*256 + SWZ(nt*16+l15, (kc*32+l4*8)*2));
                f32x4 d = {0.f,0.f,0.f,0.f};
                #pragma unroll
                for (int kc=0;kc<4;kc++) d = mfma16(bw[kc], afxi[kc], d);   // D[n][f]
                *(unsigned long long*)(&sP[l15][nt4*16 + l4*4]) = pack4_(d[0],d[1],d[2],d[3]);
            }
            bf16x8 afs0 = *(const bf16x8*)&sP[l15][l4*8];
            bf16x8 afs1 = *(const bf16x8*)&sP[l15][32+l4*8];
            #pragma unroll
            for (int gt=0; gt<7; gt++){
                int r = gt*16+l15;
                bf16x8 b0 = *(const bf16x8*)(Ln + r*256 + SWZ(r, (p*64 + l4*8)*2));
                bf16x8 b1 = *(const bf16x8*)(Ln + r*256 + SWZ(r, (p*64 + 32 + l4*8)*2));
                sc[gt] = mfma16(b0, afs0, sc[gt]);   // D[g][f]
                sc[gt] = mfma16(b1, afs1, sc[gt]);
            }
        }
        float aj = sAlpha[mt*16+l15];
        float rs = 0.f;
        #pragma unroll
        for (int gt=0; gt<7; gt++){
            f32x4 bt4 = *(const f32x4*)&sBeta[gt*16+l4*4];
            float e[4];
            #pragma unroll
            for (int j=0;j<4;j++){
                int g = gt*16 + l4*4 + j;
                float val = sc[gt][j] + aj + bt4[j] + cc;
                e[j] = (g<F_) ? __expf(sigmoidf_(val)) : 0.f;
                rs += e[j];
            }
            if (gt < 4)
                *(unsigned long long*)(&sP[l15][gt*16 + l4*4]) = pack4_(e[0],e[1],e[2],e[3]);
            else
                uexB[gt-4] = pack4_(e[0],e[1],e[2],e[3]);
        }
        rs += __shfl_xor(rs, 16, 64);
        rs += __shfl_xor(rs, 32, 64);
        if (l4 == 0) sInv[w*16 + l15] = 1.f/rs;
    } else {
        int h = lane;
        float a0=0.f, a1=0.f;
        #pragma unroll 4
        for (int f=0; f<F_; ++f){
            float awf = sAw[f];
            a0 += awf * (float)*(const bf16*)(Ln + f*256 + SWZ(f, h*2));
            a1 += awf * (float)*(const bf16*)(Ln + f*256 + SWZ(f, (h+64)*2));
        }
        xtb[(size_t)b*H_ + h]      = (bf16)(a0 * sNorm[h]);
        xtb[(size_t)b*H_ + h + 64] = (bf16)(a1 * sNorm[h+64]);
    }

    unsigned long long vpku[7];
    #pragma unroll
    for (int gt=0; gt<7; gt++){
        f32x4 acc = {0.f,0.f,0.f,0.f};
        #pragma unroll
        for (int kc=0;kc<4;kc++){
            int r = gt*16+l15;
            bf16x8 a = *(const bf16x8*)(Ln + r*256 + SWZ(r, (kc*32+l4*8)*2));
            acc = mfma16(a, awv[kc], acc);
        }
        vpku[gt] = pack4_(acc[0]+vbr, acc[1]+vbr, acc[2]+vbr, acc[3]+vbr);
    }
    __syncthreads();   // B6

    {
        int hrow = w*16 + l15;
        #pragma unroll
        for (int gt=0; gt<7; gt++)
            *(unsigned long long*)(Lm + hrow*256 + SWZ(hrow, gt*32 + l4*8)) = vpku[gt];
    }
    __syncthreads();   // B7

    if (mt < 7){
        bf16x8 ap0 = *(const bf16x8*)&sP[l15][l4*8];
        bf16x8 ap1 = *(const bf16x8*)&sP[l15][32+l4*8];
        f32x4 acc8[8];
        #pragma unroll
        for (int ht=0;ht<8;ht++) acc8[ht] = (f32x4){0.f,0.f,0.f,0.f};
        #pragma unroll
        for (int ht=0; ht<8; ht++){
            int r = ht*16+l15;
            bf16x8 bv0 = *(const bf16x8*)(Lm + r*256 + SWZ(r, (l4*8)*2));
            bf16x8 bv1 = *(const bf16x8*)(Lm + r*256 + SWZ(r, (32+l4*8)*2));
            acc8[ht] = mfma16(ap0, bv0, acc8[ht]);
            acc8[ht] = mfma16(ap1, bv1, acc8[ht]);
        }
        #pragma unroll
        for (int gt=4; gt<7; gt++)
            *(unsigned long long*)(&sP[l15][(gt-4)*16 + l4*4]) = uexB[gt-4];
        *(unsigned long long*)(&sP[l15][48 + l4*4]) = 0ull;
        bf16x8 ap2 = *(const bf16x8*)&sP[l15][l4*8];
        bf16x8 ap3 = *(const bf16x8*)&sP[l15][32+l4*8];
        #pragma unroll
        for (int ht=0; ht<8; ht++){
            int r = ht*16+l15;
            int c2 = 64+l4*8;
            int c3 = 96+l4*8;  if (c3 >= 112) c3 = 96;
            bf16x8 bv2 = *(const bf16x8*)(Lm + r*256 + SWZ(r, c2*2));
            bf16x8 bv3 = *(const bf16x8*)(Lm + r*256 + SWZ(r, c3*2));
            acc8[ht] = mfma16(ap2, bv2, acc8[ht]);
            acc8[ht] = mfma16(ap3, bv3, acc8[ht]);
        }
        float fs[4];
        #pragma unroll
        for (int j=0;j<4;j++) fs[j] = sInv[w*16 + l4*4 + j] * FP8SC;
        #pragma unroll
        for (int ht=0; ht<8; ht++){
            unsigned u = cvtfp8x4_(acc8[ht][0]*fs[0], acc8[ht][1]*fs[1], acc8[ht][2]*fs[2], acc8[ht][3]*fs[3]);
            if (mt < 6){
                *(unsigned*)(xxb + (size_t)b*KC_ + swzk_(b, (mt*8+ht)*256 + lane*4)) = u;
            } else if (l4 == 0){
                *(unsigned*)(xxb + (size_t)b*KC_ + swzk_(b, 12288 + ht*64 + l15*4)) = u;
            }
        }
    }
}

// ---------------- fp8 split-K GEMM: 128x256 tile, global_load_lds staging, baked swizzle ----------------
// grid (N/256, M/128, SPLIT) = (2,64,4) = 512 blocks. LDS 48 KB.
__global__ __launch_bounds__(512,2) void k_gemm_fp8(const unsigned char* __restrict__ A,
        const unsigned char* __restrict__ Bt, bf16* __restrict__ part, int M, int N, int K, int KS)
{
    __shared__ unsigned char S[49152];   // A rows 0..127 @128B: [0,16384); B rows 0..255: [16384,49152)
    int tid=threadIdx.x, w=tid>>6, lane=tid&63, l15=lane&15, l4=lane>>4;
    int m0 = blockIdx.y*128, n0 = blockIdx.x*256;
    int kbeg = blockIdx.z*KS, kend = kbeg + KS;
    int wr = w>>2, wc = w&3;
    // staging geometry: per instruction q, LDS off = q*8192 + w*1024 + lane*16 (lane-linear)
    int offW = w*1024 + lane*16;
    int rS = offW >> 7, cS = offW & 127;   // row-in-8K-page, col bytes
    f32x4 acc[4][4];
    #pragma unroll
    for(int mi=0;mi<4;mi++)
        #pragma unroll
        for(int ni=0;ni<4;ni++) acc[mi][ni] = (f32x4){0.f,0.f,0.f,0.f};

    int sx = (l15&7)<<4;   // consumer-side XOR (rows of fragments ≡ l15 mod 8)

    for (int k0=kbeg; k0<kend; k0+=128){
        __syncthreads();
        // A: 2 pages (rows 0..63, 64..127)
        gld16_(A + (size_t)(m0 + rS     )*K + k0 + cS, S + offW);
        gld16_(A + (size_t)(m0 + rS + 64)*K + k0 + cS, S + offW + 8192);
        // B: 4 pages (rows 0..255)
        #pragma unroll
        for (int q=0;q<4;q++)
            gld16_(Bt + (size_t)(n0 + q*64 + rS)*K + k0 + cS, S + 16384 + q*8192 + offW);
        __syncthreads();
        #pragma unroll
        for(int ks=0;ks<4;ks++){
            int co = (ks*32 + l4*8) ^ sx;
            long af[4], bfr[4];
            #pragma unroll
            for(int mi=0;mi<4;mi++) af[mi] = *(const long*)(S + (wr*64+mi*16+l15)*128 + co);
            #pragma unroll
            for(int ni=0;ni<4;ni++) bfr[ni] = *(const long*)(S + 16384 + (wc*64+ni*16+l15)*128 + co);
            #pragma unroll
            for(int mi=0;mi<4;mi++)
                #pragma unroll
                for(int ni=0;ni<4;ni++)
                    acc[mi][ni] = mfma8(af[mi], bfr[ni], acc[mi][ni]);
        }
    }
    bf16* pz = part + (size_t)blockIdx.z*M*N;
    #pragma unroll
    for(int mi=0;mi<4;mi++)
        #pragma unroll
        for(int ni=0;ni<4;ni++){
            int col = n0 + wc*64 + ni*16 + l15;
            #pragma unroll
            for(int j=0;j<4;j++){
                int row = m0 + wr*64 + mi*16 + l4*4 + j;
                pz[(size_t)row*N + col] = (bf16)acc[mi][ni][j];
            }
        }
}

// reduce SPLIT bf16 partials + bias + ELU -> bf16
__global__ void k_c1fin(const bf16* __restrict__ part, const float* __restrict__ bias,
                        bf16* __restrict__ out){
    const size_t MN = (size_t)B_*512;
    size_t e0 = ((size_t)blockIdx.x*256 + threadIdx.x)*4;
    bf16x4 p0 = *(const bf16x4*)(part + e0);
    bf16x4 p1 = *(const bf16x4*)(part + MN + e0);
    bf16x4 p2 = *(const bf16x4*)(part + 2*MN + e0);
    bf16x4 p3 = *(const bf16x4*)(part + 3*MN + e0);
    f32x4 bb = *(const f32x4*)(bias + (e0 & 511));
    const float ds = 1.0f/(FP8SC*FP8SC);
    float s0 = ((float)p0[0]+(float)p1[0]+(float)p2[0]+(float)p3[0])*ds + bb[0];
    float s1 = ((float)p0[1]+(float)p1[1]+(float)p2[1]+(float)p3[1])*ds + bb[1];
    float s2 = ((float)p0[2]+(float)p1[2]+(float)p2[2]+(float)p3[2])*ds + bb[2];
    float s3 = ((float)p0[3]+(float)p1[3]+(float)p2[3]+(float)p3[3])*ds + bb[3];
    unsigned long long u = pack4_(eluf_(s0), eluf_(s1), eluf_(s2), eluf_(s3));
    *(unsigned long long*)(out + e0) = u;
}

// ---------------- generic tiled GEMM (c2, c3) ----------------
template<int BN, bool ELU>
__global__ __launch_bounds__(256,2) void k_gemm(const bf16* __restrict__ A, const bf16* __restrict__ Bt,
        const float* __restrict__ bias, bf16* __restrict__ out, int M, int N, int K)
{
    __shared__ bf16 sAt[128][72];
    __shared__ bf16 sBt[BN][72];
    int tid=threadIdx.x, w=tid>>6, lane=tid&63, l15=lane&15, l4=lane>>4;
    int m0 = blockIdx.y*128, n0 = blockIdx.x*BN;
    constexpr int MI = (BN==128)?4:2;
    constexpr int NI = (BN==128)?4:BN/16;
    int wr = (BN==128)? (w>>1) : w;
    int wc = (BN==128)? (w&1) : 0;
    f32x4 acc[MI][NI];
    #pragma unroll
    for(int mi=0;mi<MI;mi++)
        #pragma unroll
        for(int ni=0;ni<NI;ni++) acc[mi][ni] = (f32x4){0.f,0.f,0.f,0.f};

    for (int k0=0; k0<K; k0+=64){
        __syncthreads();
        for (int t=tid; t<128*8; t+=256){
            int row=t>>3, col=(t&7)*8;
            *(bf16x8*)&sAt[row][col] = *(const bf16x8*)(A + (size_t)(m0+row)*K + k0 + col);
        }
        for (int t=tid; t<BN*8; t+=256){
            int row=t>>3, col=(t&7)*8;
            *(bf16x8*)&sBt[row][col] = *(const bf16x8*)(Bt + (size_t)(n0+row)*K + k0 + col);
        }
        __syncthreads();
        #pragma unroll
        for(int ks=0;ks<2;ks++){
            bf16x8 af[MI], bfr[NI];
            #pragma unroll
            for(int mi=0;mi<MI;mi++) af[mi] = *(const bf16x8*)&sAt[wr*(MI*16)+mi*16+l15][ks*32+l4*8];
            #pragma unroll
            for(int ni=0;ni<NI;ni++) bfr[ni] = *(const bf16x8*)&sBt[wc*64+ni*16+l15][ks*32+l4*8];
            #pragma unroll
            for(int mi=0;mi<MI;mi++)
                #pragma unroll
                for(int ni=0;ni<NI;ni++)
                    acc[mi][ni] = mfma16(af[mi], bfr[ni], acc[mi][ni]);
        }
    }
    #pragma unroll
    for(int mi=0;mi<MI;mi++)
        #pragma unroll
        for(int ni=0;ni<NI;ni++){
            int col = n0 + wc*64 + ni*16 + l15;
            float bc = bias[col];
            #pragma unroll
            for(int j=0;j<4;j++){
                int row = m0 + wr*(MI*16) + mi*16 + l4*4 + j;
                float v = acc[mi][ni][j] + bc;
                if (ELU) v = eluf_(v);
                out[(size_t)row*N + col] = (bf16)v;
            }
        }
}

// ---------------- merged tails ----------------
__global__ __launch_bounds__(256,2) void k_tails(const bf16* __restrict__ c3o,
    const float* __restrict__ c4w, const float* __restrict__ c4b,
    const float* __restrict__ c5w, const float* __restrict__ c5b,
    const float* __restrict__ clw, const float* __restrict__ clb,
    const float* __restrict__ ctw, const float* __restrict__ ctb,
    const bf16* __restrict__ xtb,
    const float* __restrict__ u1w, const float* __restrict__ u1b,
    const float* __restrict__ u2w, const float* __restrict__ u2b,
    const float* __restrict__ u3w, const float* __restrict__ u3b,
    const float* __restrict__ u4w, const float* __restrict__ u4b,
    const float* __restrict__ tlw, const float* __restrict__ tlb,
    const float* __restrict__ utw, const float* __restrict__ utb, float* __restrict__ outp)
{
    __shared__ char A[58880];
    int tid = threadIdx.x, blk = blockIdx.x;
    int r0 = (blk>>1)*32;
    if ((blk & 1) == 0){
        float (*sA)[260] = (float(*)[260])A;
        float (*sB)[132] = (float(*)[132])(A + 33280);
        float (*sC)[68]  = (float(*)[68])(A + 50176);
        for (int v=tid; v<32*64; v+=256){
            int r=v>>6, c=(v&63)*4;
            bf16x4 x = *(const bf16x4*)(c3o + (size_t)(r0+r)*256 + c);
            sA[r][c]=(float)x[0]; sA[r][c+1]=(float)x[1]; sA[r][c+2]=(float)x[2]; sA[r][c+3]=(float)x[3];
        }
        __syncthreads();
        {
            int j = tid&127, rb = tid>>7;
            float acc[16];
            #pragma unroll
            for (int i=0;i<16;i++) acc[i]=c4b[j];
            #pragma unroll 4
            for (int h=0;h<256;h++){
                float wv = c4w[h*128+j];
                #pragma unroll
                for (int i=0;i<16;i++) acc[i] += sA[2*i+rb][h]*wv;
            }
            #pragma unroll
            for (int i=0;i<16;i++) sB[2*i+rb][j] = eluf_(acc[i]);
        }
        __syncthreads();
        {
            int j = tid&63, rb = tid>>6;
            float acc[8];
            #pragma unroll
            for (int i=0;i<8;i++) acc[i]=c5b[j];
            #pragma unroll 4
            for (int h=0;h<128;h++){
                float wv = c5w[h*64+j];
                #pragma unroll
                for (int i=0;i<8;i++) acc[i] += sB[4*i+rb][h]*wv;
            }
            #pragma unroll
            for (int i=0;i<8;i++) sC[4*i+rb][j] = eluf_(acc[i]);
        }
        __syncthreads();
        if (tid < 32){
            float r1 = clb[0], r2 = ctb[0];
            #pragma unroll 8
            for (int k=0;k<64;k++){ float v = sC[tid][k]; r1 += v*clw[k]; r2 += v*ctw[k]; }
            int row = r0 + tid;
            outp[row] = r1;
            outp[B_ + row] = sigmoidf_(r1);
            outp[(size_t)2*B_ + row] = r2;
        }
    } else {
        float (*sA)[132] = (float(*)[132])A;
        float (*sB)[132] = (float(*)[132])(A + 16896);
        float (*sC)[68]  = (float(*)[68])(A + 33792);
        float (*sD)[36]  = (float(*)[36])(A + 42496);
        float (*sE)[20]  = (float(*)[20])(A + 47104);
        for (int v=tid; v<32*32; v+=256){
            int r=v>>5, c=(v&31)*4;
            bf16x4 x = *(const bf16x4*)(xtb + (size_t)(r0+r)*128 + c);
            sA[r][c]=(float)x[0]; sA[r][c+1]=(float)x[1]; sA[r][c+2]=(float)x[2]; sA[r][c+3]=(float)x[3];
        }
        __syncthreads();
        {
            int j = tid&127, rb = tid>>7;
            float acc[16];
            #pragma unroll
            for (int i=0;i<16;i++) acc[i]=u1b[j];
            #pragma unroll 4
            for (int h=0;h<128;h++){
                float wv = u1w[h*128+j];
                #pragma unroll
                for (int i=0;i<16;i++) acc[i] += sA[2*i+rb][h]*wv;
            }
            #pragma unroll
            for (int i=0;i<16;i++) sB[2*i+rb][j] = eluf_(acc[i]);
        }
        __syncthreads();
        {
            int j = tid&63, rb = tid>>6;
            float acc[8];
            #pragma unroll
            for (int i=0;i<8;i++) acc[i]=u2b[j];
            #pragma unroll 4
            for (int h=0;h<128;h++){
                float wv = u2w[h*64+j];
                #pragma unroll
                for (int i=0;i<8;i++) acc[i] += sB[4*i+rb][h]*wv;
            }
            #pragma unroll
            for (int i=0;i<8;i++) sC[4*i+rb][j] = eluf_(acc[i]);
        }
        __syncthreads();
        {
            int j = tid&31, rb = tid>>5;
            float acc[4];
            #pragma unroll
            for (int i=0;i<4;i++) acc[i]=u3b[j];
            #pragma unroll 4
            for (int h=0;h<64;h++){
                float wv = u3w[h*32+j];
                #pragma unroll
                for (int i=0;i<4;i++) acc[i] += sC[8*i+rb][h]*wv;
            }
            #pragma unroll
            for (int i=0;i<4;i++) sD[8*i+rb][j] = eluf_(acc[i]);
        }
        __syncthreads();
        {
            int j = tid&15, rb = tid>>4;
            float acc0=u4b[j], acc1=u4b[j];
            #pragma unroll 4
            for (int h=0;h<32;h++){
                float wv = u4w[h*16+j];
                acc0 += sD[rb][h]*wv;
                acc1 += sD[16+rb][h]*wv;
            }
            sE[rb][j] = eluf_(acc0);
            sE[16+rb][j] = eluf_(acc1);
        }
        __syncthreads();
        if (tid < 32){
            float r1 = tlb[0], r2 = utb[0];
            #pragma unroll
            for (int k=0;k<16;k++){ float v = sE[tid][k]; r1 += v*tlw[k]; r2 += v*utw[k]; }
            int row = r0 + tid;
            outp[(size_t)3*B_ + row] = r1;
            outp[(size_t)4*B_ + row] = sigmoidf_(r1);
            outp[(size_t)5*B_ + row] = r2;
        }
    }
}

extern "C" void kernel_launch(void* const* d_in, const int* in_sizes, int n_in,
                              void* d_out, int out_size, void* d_ws, size_t ws_size,
                              hipStream_t stream) {
    const float* feat=(const float*)d_in[0];
    const float* emb =(const float*)d_in[2];
    const float* t_w =(const float*)d_in[3]; const float* t_b=(const float*)d_in[4];
    const float* qw  =(const float*)d_in[5]; const float* qb =(const float*)d_in[6];
    const float* kw  =(const float*)d_in[7]; const float* kb =(const float*)d_in[8];
    const float* vw  =(const float*)d_in[9]; const float* vb =(const float*)d_in[10];
    const float* a1w =(const float*)d_in[11];
    const float* a2w =(const float*)d_in[12]; const float* a2b=(const float*)d_in[13];
    const float* a3w =(const float*)d_in[14];
    const float* c1w =(const float*)d_in[15]; const float* c1b=(const float*)d_in[16];
    const float* c2w =(const float*)d_in[17]; const float* c2b=(const float*)d_in[18];
    const float* c3w =(const float*)d_in[19]; const float* c3b=(const float*)d_in[20];
    const float* c4w =(const float*)d_in[21]; const float* c4b=(const float*)d_in[22];
    const float* c5w =(const float*)d_in[23]; const float* c5b=(const float*)d_in[24];
    const float* clw =(const float*)d_in[25]; const float* clb=(const float*)d_in[26];
    const float* ctw =(const float*)d_in[27]; const float* ctb=(const float*)d_in[28];
    const float* u1w =(const float*)d_in[29]; const float* u1b=(const float*)d_in[30];
    const float* u2w =(const float*)d_in[31]; const float* u2b=(const float*)d_in[32];
    const float* u3w =(const float*)d_in[33]; const float* u3b=(const float*)d_in[34];
    const float* u4w =(const float*)d_in[35]; const float* u4b=(const float*)d_in[36];
    const float* tlw =(const float*)d_in[37]; const float* tlb=(const float*)d_in[38];
    const float* utw =(const float*)d_in[39]; const float* utb=(const float*)d_in[40];
    float* outp = (float*)d_out;

    char* ws = (char*)d_ws;
    size_t off = 0;
    auto alloc = [&](size_t bytes)->char*{ char* p = ws + off; off += (bytes + 255) & ~(size_t)255; return p; };
    unsigned char* xxb = (unsigned char*)alloc((size_t)B_*KC_);
    bf16* part   = (bf16*)alloc((size_t)SPLIT_*B_*512*2);
    float* attg  = (float*)alloc((size_t)B_*FP*4);
    bf16* xtb    = (bf16*)alloc((size_t)B_*128*2);
    bf16* cbuf1  = (bf16*)alloc((size_t)B_*512*2);
    bf16* mextT  = (bf16*)alloc(144*128*2);
    bf16* wvT    = (bf16*)alloc(128*128*2);
    bf16* wa2t   = (bf16*)alloc(128*128*2);
    unsigned char* c1wtk8 = (unsigned char*)alloc((size_t)512*KC_);
    bf16* c2wt   = (bf16*)alloc((size_t)512*512*2);
    bf16* c3wt   = (bf16*)alloc((size_t)512*256*2);
    float* sigt  = (float*)alloc(128*4);
    float* cconst= (float*)alloc(4);
    bf16* cbuf2 = (bf16*)(xxb);
    bf16* cbuf3 = (bf16*)(xxb + (16u<<20));
    (void)ws_size; (void)in_sizes; (void)n_in; (void)out_size;

    k_prep_all<<<426,256,0,stream>>>(qw,qb,kw,kb,t_w,t_b,a1w, vw, a2w, c2w, c3w,
                                     mextT, sigt, cconst, wvT, wa2t, c2wt, c3wt);

    k_gk<<<13568,256,0,stream>>>(c1w, c1wtk8, feat, emb, wa2t, a2b, a3w, sigt, attg);

    k_attn2<<<B_,512,0,stream>>>(feat,emb,mextT,wvT,vb,cconst,attg, xxb, xtb);

    k_gemm_fp8<<<dim3(2,64,SPLIT_),512,0,stream>>>(xxb, c1wtk8, part, B_,512,KC_, KC_/SPLIT_);
    k_c1fin<<<4096,256,0,stream>>>(part, c1b, cbuf1);

    k_gemm<128,true><<<dim3(4,64),256,0,stream>>>(cbuf1, c2wt, c2b, cbuf2, B_,512,512);
    k_gemm<64,true><<<dim3(4,64),256,0,stream>>>(cbuf2, c3wt, c3b, cbuf3, B_,256,512);

    k_tails<<<512,256,0,stream>>>(cbuf3,c4w,c4b,c5w,c5b,clw,clb,ctw,ctb,
                                  xtb,u1w,u1b,u2w,u2b,u3w,u3b,u4w,u4b,tlw,tlb,utw,utb,outp);
}

// Round 20
// 596.589 us; speedup vs baseline: 1.3055x; 1.0405x over previous
//
#include <hip/hip_runtime.h>
#include <hip/hip_bf16.h>

typedef __bf16 bf16;
typedef __bf16 bf16x8 __attribute__((ext_vector_type(8)));
typedef __bf16 bf16x4 __attribute__((ext_vector_type(4)));
typedef float f32x4 __attribute__((ext_vector_type(4)));
typedef unsigned u32x4 __attribute__((ext_vector_type(4)));

#define DEVI static __device__ __forceinline__

DEVI float sigmoidf_(float x){ return 1.0f/(1.0f+__expf(-x)); }
DEVI float eluf_(float x){ return x>0.f ? x : (__expf(x)-1.f); }
DEVI f32x4 mfma16(bf16x8 a, bf16x8 b, f32x4 c){ return __builtin_amdgcn_mfma_f32_16x16x32_bf16(a,b,c,0,0,0); }
DEVI f32x4 mfma8(long a, long b, f32x4 c){ return __builtin_amdgcn_mfma_f32_16x16x32_fp8_fp8(a,b,c,0,0,0); }
DEVI unsigned pack2_(float a, float b){
    union { bf16 v[2]; unsigned u; } t; t.v[0]=(bf16)a; t.v[1]=(bf16)b; return t.u;
}
DEVI unsigned long long pack4_(float a, float b, float c, float d){
    union { bf16 v[4]; unsigned long long u; } t;
    t.v[0]=(bf16)a; t.v[1]=(bf16)b; t.v[2]=(bf16)c; t.v[3]=(bf16)d; return t.u;
}
DEVI unsigned cvtfp8x4_(float a, float b, float c, float d){
    int v = __builtin_amdgcn_cvt_pk_fp8_f32(a, b, 0, false);
    v = __builtin_amdgcn_cvt_pk_fp8_f32(c, d, v, true);
    return (unsigned)v;
}
// async global->LDS, 16 B per lane
DEVI void gld16_(const void* g, void* l){
    __builtin_amdgcn_global_load_lds((const __attribute__((address_space(1))) void*)g,
                                     (__attribute__((address_space(3))) void*)l, 16, 0, 0);
}

#define B_ 8192
#define F_ 100
#define FP 112
#define H_ 128
#define KC_ 12800
#define SPLIT_ 4
#define FP8SC 16.0f

#define SWZ(r,bc) ((bc) ^ (((r)&7)<<4))
// byte-offset swizzle within each 128-B chunk, keyed by row
DEVI int swzk_(int row, int k){ return (k & ~127) | ((k & 127) ^ ((row&7)<<4)); }

// ---------------- mega weight prep ----------------
DEVI void dotrans_(float (*t)[33], const float* in, bf16* out, int R, int C, int bx, int by, int tid){
    int c0 = bx*32, r0 = by*32;
    int tc = tid & 31, tr = tid >> 5;
    #pragma unroll
    for (int i=0;i<4;i++){
        int r = tr + i*8;
        t[r][tc] = in[(size_t)(r0+r)*C + c0 + tc];
    }
    __syncthreads();
    #pragma unroll
    for (int i=0;i<4;i++){
        int ro = tr + i*8;
        out[(size_t)(c0+ro)*R + r0 + tc] = (bf16)t[tc][ro];
    }
}

// transpose with baked per-row chunk swizzle (for gld16-consumed weights)
DEVI void dotrans_swz_(float (*t)[33], const float* in, bf16* out, int R, int C, int bx, int by, int tid){
    int c0 = bx*32, r0 = by*32;
    int tc = tid & 31, tr = tid >> 5;
    #pragma unroll
    for (int i=0;i<4;i++){
        int r = tr + i*8;
        t[r][tc] = in[(size_t)(r0+r)*C + c0 + tc];
    }
    __syncthreads();
    #pragma unroll
    for (int i=0;i<4;i++){
        int ro = tr + i*8;
        int n = c0+ro;
        int ob = swzk_(n, (r0+tc)*2);
        *(bf16*)((char*)out + (size_t)n*R*2 + ob) = (bf16)t[tc][ro];
    }
}

__global__ void k_prep_all(const float* __restrict__ qw, const float* __restrict__ qb,
                           const float* __restrict__ kw, const float* __restrict__ kb,
                           const float* __restrict__ tw, const float* __restrict__ tb,
                           const float* __restrict__ a1w, const float* __restrict__ vw,
                           const float* __restrict__ a2w, const float* __restrict__ c2w,
                           const float* __restrict__ c3w,
                           bf16* __restrict__ mextT, float* __restrict__ sigt, float* __restrict__ cconst,
                           bf16* __restrict__ wvT, bf16* __restrict__ wa2t,
                           bf16* __restrict__ c2wt, bf16* __restrict__ c3wt){
    __shared__ float t[32][33];
    const float rsc = 0.08838834764831845f;
    int blk = blockIdx.x, tid = threadIdx.x;
    if (blk < 9){
        #pragma unroll 1
        for (int e=0; e<8; ++e){
            int idx = e*256 + tid;
            int n = blk*16 + (idx>>7), h = idx&127;
            float acc = 0.f;
            if (n < 128){
                for (int d=0; d<128; ++d) acc += qw[h*128+d]*kw[n*128+d];
            } else if (n == 128){
                for (int d=0; d<128; ++d) acc += qw[h*128+d]*kb[d];
            } else if (n == 129){
                for (int d=0; d<128; ++d) acc += kw[h*128+d]*qb[d];
            }
            mextT[n*128+h] = (bf16)(acc*rsc);
        }
    } else if (blk == 9){
        if (tid < 128){
            float acc = 0.f;
            for (int h=0; h<128; ++h) acc += (tw[h]+tb[h]) * a1w[h*128+tid];
            sigt[tid] = sigmoidf_(acc);
        } else if (tid == 128){
            float acc = 0.f;
            for (int d=0; d<128; ++d) acc += qb[d]*kb[d];
            cconst[0] = acc*rsc;
        }
    } else if (blk < 26){
        int i = blk-10; dotrans_(t, vw, wvT, 128,128, i&3, i>>2, tid);
    } else if (blk < 42){
        int i = blk-26; dotrans_(t, a2w, wa2t, 128,128, i&3, i>>2, tid);
    } else if (blk < 298){
        int i = blk-42; dotrans_swz_(t, c2w, c2wt, 512,512, i&15, i>>4, tid);
    } else {
        int i = blk-298; dotrans_swz_(t, c3w, c3wt, 512,256, i&7, i>>3, tid);
    }
}

// compact kappa: bijection on [0,12800)
DEVI int kappa_(int k){
    int f = k>>7, h = k&127;
    if (f < 96)
        return (((f>>4)<<3) | (h>>4))*256 + ((f&15)>>2)*64 + (h&15)*4 + (f&3);
    else
        return 12288 + (h>>4)*64 + (h&15)*4 + (f&3);
}

// ---------------- merged: c1w kappa-fp8 prep (blocks 0..6399) + gatt GEMM (6400..13567) ----------------
__global__ __launch_bounds__(256,2) void k_gk(
    const float* __restrict__ c1w, unsigned char* __restrict__ c1wtk8,
    const float* __restrict__ feat, const float* __restrict__ emb,
    const bf16* __restrict__ wa2t, const float* __restrict__ a2b,
    const float* __restrict__ a3w, const float* __restrict__ sigt,
    float* __restrict__ attg)
{
    __shared__ char A[37888];
    int blk = blockIdx.x, tid = threadIdx.x;
    if (blk < 6400){
        float (*t)[33] = (float(*)[33])A;
        const int C = 512;
        int c0 = (blk&15)*32, r0 = (blk>>4)*32;
        int tc = tid & 31, tr = tid >> 5;
        #pragma unroll
        for (int i=0;i<4;i++){
            int r = tr + i*8;
            t[r][tc] = c1w[(size_t)(r0+r)*C + c0 + tc];
        }
        __syncthreads();
        #pragma unroll
        for (int i=0;i<4;i++){
            int ro = tr + i*8;
            float x = t[tc][ro]*FP8SC;
            int v = __builtin_amdgcn_cvt_pk_fp8_f32(x, x, 0, false);
            int n = c0+ro;
            c1wtk8[(size_t)n*KC_ + swzk_(n, kappa_(r0+tc))] = (unsigned char)v;
        }
        return;
    }
    bf16 (*sAt)[72] = (bf16(*)[72])A;
    bf16 (*sBt)[72] = (bf16(*)[72])(A + 18432);
    float (*sRed)[128] = (float(*)[128])(A + 36864);
    int w=tid>>6, lane=tid&63, l15=lane&15, l4=lane>>4;
    int m0 = (blk-6400)*128;
    int wr = w>>1, wc = w&1;
    f32x4 acc[4][4];
    #pragma unroll
    for(int mi=0;mi<4;mi++)
        #pragma unroll
        for(int ni=0;ni<4;ni++) acc[mi][ni] = (f32x4){0.f,0.f,0.f,0.f};

    #pragma unroll 1
    for (int k0=0; k0<128; k0+=64){
        __syncthreads();
        #pragma unroll
        for (int t4=0; t4<4; t4++){
            int t = tid + t4*256;
            int row=t>>3, col=(t&7)*8;
            int gr = m0+row;
            int bb = gr/112, ff = gr - bb*112;
            bf16x8 o;
            if (ff < F_){
                float fv = feat[(size_t)bb*F_ + ff];
                const float* ep = emb + ff*H_ + k0 + col;
                f32x4 e0 = *(const f32x4*)ep;
                f32x4 e1 = *(const f32x4*)(ep+4);
                o[0]=(bf16)(fv*e0[0]); o[1]=(bf16)(fv*e0[1]); o[2]=(bf16)(fv*e0[2]); o[3]=(bf16)(fv*e0[3]);
                o[4]=(bf16)(fv*e1[0]); o[5]=(bf16)(fv*e1[1]); o[6]=(bf16)(fv*e1[2]); o[7]=(bf16)(fv*e1[3]);
            } else {
                #pragma unroll
                for (int e=0;e<8;e++) o[e]=(bf16)0.f;
            }
            *(bf16x8*)&sAt[row][col] = o;
            *(bf16x8*)&sBt[row][col] = *(const bf16x8*)(wa2t + row*H_ + k0 + col);
        }
        __syncthreads();
        #pragma unroll
        for(int ks=0;ks<2;ks++){
            bf16x8 af[4], bfr[4];
            #pragma unroll
            for(int mi=0;mi<4;mi++) af[mi] = *(const bf16x8*)&sAt[wr*64+mi*16+l15][ks*32+l4*8];
            #pragma unroll
            for(int ni=0;ni<4;ni++) bfr[ni] = *(const bf16x8*)&sBt[wc*64+ni*16+l15][ks*32+l4*8];
            #pragma unroll
            for(int mi=0;mi<4;mi++)
                #pragma unroll
                for(int ni=0;ni<4;ni++)
                    acc[mi][ni] = mfma16(af[mi], bfr[ni], acc[mi][ni]);
        }
    }
    float sg[4], ab[4], a3[4];
    #pragma unroll
    for (int ni=0;ni<4;ni++){
        int n = wc*64 + ni*16 + l15;
        sg[ni]=sigt[n]; ab[ni]=a2b[n]; a3[ni]=a3w[n];
    }
    #pragma unroll
    for (int mi=0;mi<4;mi++){
        float sj[4] = {0.f,0.f,0.f,0.f};
        #pragma unroll
        for (int ni=0;ni<4;ni++){
            #pragma unroll
            for (int j=0;j<4;j++){
                float u = sigmoidf_(acc[mi][ni][j] + ab[ni]);
                float t = sg[ni] + u;
                t = t>0.f ? t : 0.f;
                sj[j] += t*a3[ni];
            }
        }
        #pragma unroll
        for (int j=0;j<4;j++){
            float v = sj[j];
            #pragma unroll
            for (int m=1;m<16;m<<=1) v += __shfl_xor(v,m,16);
            sj[j]=v;
        }
        if (l15==0){
            #pragma unroll
            for (int j=0;j<4;j++) sRed[wc][wr*64+mi*16+l4*4+j] = sj[j];
        }
    }
    __syncthreads();
    if (tid < 128) attg[(size_t)m0 + tid] = sRed[0][tid] + sRed[1][tid];
}

// ---------------- fused per-batch attention (unchanged from R19) ----------------
__global__ __launch_bounds__(512,2) void k_attn2(
    const float* __restrict__ feat, const float* __restrict__ emb,
    const bf16* __restrict__ mextT, const bf16* __restrict__ wvT,
    const float* __restrict__ vb, const float* __restrict__ cconst,
    const float* __restrict__ attg,
    unsigned char* __restrict__ xxb, bf16* __restrict__ xtb)
{
    __shared__ char L[81792];
    char* Lm = L;
    char* Ln = L + 32768;
    float* sFeat  = (float*)(L+61440);
    float* normP  = (float*)(L+62336);   // [8][128] f32
    float* sAw    = (float*)(L+77568);   // wave-7 sP slot
    float* sNorm  = (float*)(L+79872);
    float* sAlpha = (float*)(L+80384);
    float* sBeta  = (float*)(L+80832);
    float* sInv   = (float*)(L+81280);   // [8][16]

    int b = blockIdx.x;
    int tid = threadIdx.x, w = tid>>6, lane = tid&63;
    int l15 = lane&15, l4 = lane>>4;
    bf16 (*sP)[72] = (bf16(*)[72])(L + 61440 + w*2304);

    bf16x8 awv[4];
    #pragma unroll
    for (int kc=0;kc<4;kc++)
        awv[kc] = *(const bf16x8*)(wvT + (w*16+l15)*H_ + kc*32 + l4*8);
    float vbr = vb[w*16+l15];

    #pragma unroll 2
    for (int v = tid; v < 128*16; v += 512){
        int n = v >> 4, cg = (v & 15) * 8;
        *(u32x4*)(Lm + n*256 + SWZ(n, cg*2)) = *(const u32x4*)(mextT + n*128 + cg);
    }
    if (tid < FP) sFeat[tid] = (tid<F_) ? feat[(size_t)b*F_+tid] : 0.f;
    if (w==0){
        const float* ag = attg + (size_t)b*FP;
        float a0 = (lane<F_)? ag[lane] : -1e30f;
        float a1 = (lane+64<F_)? ag[lane+64] : -1e30f;
        float m = fmaxf(a0,a1);
        #pragma unroll
        for(int s=1;s<64;s<<=1) m = fmaxf(m, __shfl_xor(m,s,64));
        float e0 = (lane<F_)? __expf(a0-m):0.f;
        float e1 = (lane+64<F_)? __expf(a1-m):0.f;
        float s = e0+e1;
        #pragma unroll
        for(int t=1;t<64;t<<=1) s += __shfl_xor(s,t,64);
        float inv = 1.f/s;
        if (lane<FP) sAw[lane] = e0*inv;
        if (lane+64<FP) sAw[lane+64] = e1*inv;
    }
    __syncthreads();   // B1

    int hp = (tid&63)*2, gg = tid>>6;
    {
        float fa0=0.f, fa1=0.f;
        #pragma unroll 4
        for (int it=0; it<13; ++it){
            int f = gg + 8*it;
            if (f < F_){
                float2 e2 = *(const float2*)(emb + f*H_ + hp);
                float v0 = sFeat[f]*e2.x, v1 = sFeat[f]*e2.y;
                fa0 += v0*v0; fa1 += v1*v1;
            }
        }
        *(float2*)(normP + gg*128 + hp) = make_float2(fa0, fa1);
    }
    __syncthreads();   // B2
    if (tid < 128){
        float s = 0.f;
        #pragma unroll
        for (int g2=0; g2<8; ++g2) s += normP[g2*128 + tid];
        sNorm[tid] = sqrtf(s);
    }
    __syncthreads();   // B3

    {
        float rn0 = __builtin_amdgcn_rcpf(sNorm[hp]);
        float rn1 = __builtin_amdgcn_rcpf(sNorm[hp+1]);
        #pragma unroll 4
        for (int it=0; it<13; ++it){
            int f = gg + 8*it;
            if (f < F_){
                float2 e2 = *(const float2*)(emb + f*H_ + hp);
                *(unsigned*)(Ln + f*256 + SWZ(f, hp*2)) = pack2_(sFeat[f]*e2.x*rn0, sFeat[f]*e2.y*rn1);
            }
        }
        for (int z=tid; z<768; z+=512){
            int f = 100 + (z>>6), hz = (z&63)*2;
            *(unsigned*)(Ln + f*256 + SWZ(f, hz*2)) = 0u;
        }
    }
    __syncthreads();   // B4

    int mt = w;

    if (mt < 7){
        bf16x8 bfr8[4];
        #pragma unroll
        for (int kc=0;kc<4;kc++)
            bfr8[kc] = *(const bf16x8*)(mextT + (128+(l15&1))*H_ + kc*32 + l4*8);
        f32x4 acc = {0.f,0.f,0.f,0.f};
        #pragma unroll
        for (int kc=0;kc<4;kc++){
            bf16x8 a = *(const bf16x8*)(Ln + (mt*16+l15)*256 + SWZ(mt*16+l15, (kc*32+l4*8)*2));
            acc = mfma16(a, bfr8[kc], acc);
        }
        if (l15==0){
            #pragma unroll
            for (int j=0;j<4;j++) sAlpha[mt*16+l4*4+j] = acc[j];
        }
        if (l15==1){
            #pragma unroll
            for (int j=0;j<4;j++) sBeta[mt*16+l4*4+j] = acc[j];
        }
    }
    __syncthreads();   // B5

    const float cc = cconst[0];
    unsigned long long uexB[3];
    if (mt < 7){
        bf16x8 afxi[4];
        #pragma unroll
        for (int kc=0;kc<4;kc++)
            afxi[kc] = *(const bf16x8*)(Ln + (mt*16+l15)*256 + SWZ(mt*16+l15, (kc*32+l4*8)*2));
        f32x4 sc[7];
        #pragma unroll
        for (int gt=0; gt<7; gt++) sc[gt] = (f32x4){0.f,0.f,0.f,0.f};
        #pragma unroll 1
        for (int p=0; p<2; p++){
            #pragma unroll 2
            for (int nt4=0; nt4<4; nt4++){
                int nt = p*4 + nt4;
                bf16x8 bw[4];
                #pragma unroll
                for (int kc=0;kc<4;kc++)
                    bw[kc] = *(const bf16x8*)(Lm + (nt*16+l15)*256 + SWZ(nt*16+l15, (kc*32+l4*8)*2));
                f32x4 d = {0.f,0.f,0.f,0.f};
                #pragma unroll
                for (int kc=0;kc<4;kc++) d = mfma16(bw[kc], afxi[kc], d);   // D[n][f]
                *(unsigned long long*)(&sP[l15][nt4*16 + l4*4]) = pack4_(d[0],d[1],d[2],d[3]);
            }
            bf16x8 afs0 = *(const bf16x8*)&sP[l15][l4*8];
            bf16x8 afs1 = *(const bf16x8*)&sP[l15][32+l4*8];
            #pragma unroll
            for (int gt=0; gt<7; gt++){
                int r = gt*16+l15;
                bf16x8 b0 = *(const bf16x8*)(Ln + r*256 + SWZ(r, (p*64 + l4*8)*2));
                bf16x8 b1 = *(const bf16x8*)(Ln + r*256 + SWZ(r, (p*64 + 32 + l4*8)*2));
                sc[gt] = mfma16(b0, afs0, sc[gt]);   // D[g][f]
                sc[gt] = mfma16(b1, afs1, sc[gt]);
            }
        }
        float aj = sAlpha[mt*16+l15];
        float rs = 0.f;
        #pragma unroll
        for (int gt=0; gt<7; gt++){
            f32x4 bt4 = *(const f32x4*)&sBeta[gt*16+l4*4];
            float e[4];
            #pragma unroll
            for (int j=0;j<4;j++){
                int g = gt*16 + l4*4 + j;
                float val = sc[gt][j] + aj + bt4[j] + cc;
                e[j] = (g<F_) ? __expf(sigmoidf_(val)) : 0.f;
                rs += e[j];
            }
            if (gt < 4)
                *(unsigned long long*)(&sP[l15][gt*16 + l4*4]) = pack4_(e[0],e[1],e[2],e[3]);
            else
                uexB[gt-4] = pack4_(e[0],e[1],e[2],e[3]);
        }
        rs += __shfl_xor(rs, 16, 64);
        rs += __shfl_xor(rs, 32, 64);
        if (l4 == 0) sInv[w*16 + l15] = 1.f/rs;
    } else {
        int h = lane;
        float a0=0.f, a1=0.f;
        #pragma unroll 4
        for (int f=0; f<F_; ++f){
            float awf = sAw[f];
            a0 += awf * (float)*(const bf16*)(Ln + f*256 + SWZ(f, h*2));
            a1 += awf * (float)*(const bf16*)(Ln + f*256 + SWZ(f, (h+64)*2));
        }
        xtb[(size_t)b*H_ + h]      = (bf16)(a0 * sNorm[h]);
        xtb[(size_t)b*H_ + h + 64] = (bf16)(a1 * sNorm[h+64]);
    }

    unsigned long long vpku[7];
    #pragma unroll
    for (int gt=0; gt<7; gt++){
        f32x4 acc = {0.f,0.f,0.f,0.f};
        #pragma unroll
        for (int kc=0;kc<4;kc++){
            int r = gt*16+l15;
            bf16x8 a = *(const bf16x8*)(Ln + r*256 + SWZ(r, (kc*32+l4*8)*2));
            acc = mfma16(a, awv[kc], acc);
        }
        vpku[gt] = pack4_(acc[0]+vbr, acc[1]+vbr, acc[2]+vbr, acc[3]+vbr);
    }
    __syncthreads();   // B6

    {
        int hrow = w*16 + l15;
        #pragma unroll
        for (int gt=0; gt<7; gt++)
            *(unsigned long long*)(Lm + hrow*256 + SWZ(hrow, gt*32 + l4*8)) = vpku[gt];
    }
    __syncthreads();   // B7

    if (mt < 7){
        bf16x8 ap0 = *(const bf16x8*)&sP[l15][l4*8];
        bf16x8 ap1 = *(const bf16x8*)&sP[l15][32+l4*8];
        f32x4 acc8[8];
        #pragma unroll
        for (int ht=0;ht<8;ht++) acc8[ht] = (f32x4){0.f,0.f,0.f,0.f};
        #pragma unroll
        for (int ht=0; ht<8; ht++){
            int r = ht*16+l15;
            bf16x8 bv0 = *(const bf16x8*)(Lm + r*256 + SWZ(r, (l4*8)*2));
            bf16x8 bv1 = *(const bf16x8*)(Lm + r*256 + SWZ(r, (32+l4*8)*2));
            acc8[ht] = mfma16(ap0, bv0, acc8[ht]);
            acc8[ht] = mfma16(ap1, bv1, acc8[ht]);
        }
        #pragma unroll
        for (int gt=4; gt<7; gt++)
            *(unsigned long long*)(&sP[l15][(gt-4)*16 + l4*4]) = uexB[gt-4];
        *(unsigned long long*)(&sP[l15][48 + l4*4]) = 0ull;
        bf16x8 ap2 = *(const bf16x8*)&sP[l15][l4*8];
        bf16x8 ap3 = *(const bf16x8*)&sP[l15][32+l4*8];
        #pragma unroll
        for (int ht=0; ht<8; ht++){
            int r = ht*16+l15;
            int c2 = 64+l4*8;
            int c3 = 96+l4*8;  if (c3 >= 112) c3 = 96;
            bf16x8 bv2 = *(const bf16x8*)(Lm + r*256 + SWZ(r, c2*2));
            bf16x8 bv3 = *(const bf16x8*)(Lm + r*256 + SWZ(r, c3*2));
            acc8[ht] = mfma16(ap2, bv2, acc8[ht]);
            acc8[ht] = mfma16(ap3, bv3, acc8[ht]);
        }
        float fs[4];
        #pragma unroll
        for (int j=0;j<4;j++) fs[j] = sInv[w*16 + l4*4 + j] * FP8SC;
        #pragma unroll
        for (int ht=0; ht<8; ht++){
            unsigned u = cvtfp8x4_(acc8[ht][0]*fs[0], acc8[ht][1]*fs[1], acc8[ht][2]*fs[2], acc8[ht][3]*fs[3]);
            if (mt < 6){
                *(unsigned*)(xxb + (size_t)b*KC_ + swzk_(b, (mt*8+ht)*256 + lane*4)) = u;
            } else if (l4 == 0){
                *(unsigned*)(xxb + (size_t)b*KC_ + swzk_(b, 12288 + ht*64 + l15*4)) = u;
            }
        }
    }
}

// ---------------- fp8 split-K GEMM: global_load_lds staging (unchanged from R19) ----------------
__global__ __launch_bounds__(512,2) void k_gemm_fp8(const unsigned char* __restrict__ A,
        const unsigned char* __restrict__ Bt, bf16* __restrict__ part, int M, int N, int K, int KS)
{
    __shared__ unsigned char S[49152];
    int tid=threadIdx.x, w=tid>>6, lane=tid&63, l15=lane&15, l4=lane>>4;
    int m0 = blockIdx.y*128, n0 = blockIdx.x*256;
    int kbeg = blockIdx.z*KS, kend = kbeg + KS;
    int wr = w>>2, wc = w&3;
    int offW = w*1024 + lane*16;
    int rS = offW >> 7, cS = offW & 127;
    f32x4 acc[4][4];
    #pragma unroll
    for(int mi=0;mi<4;mi++)
        #pragma unroll
        for(int ni=0;ni<4;ni++) acc[mi][ni] = (f32x4){0.f,0.f,0.f,0.f};

    int sx = (l15&7)<<4;

    for (int k0=kbeg; k0<kend; k0+=128){
        __syncthreads();
        gld16_(A + (size_t)(m0 + rS     )*K + k0 + cS, S + offW);
        gld16_(A + (size_t)(m0 + rS + 64)*K + k0 + cS, S + offW + 8192);
        #pragma unroll
        for (int q=0;q<4;q++)
            gld16_(Bt + (size_t)(n0 + q*64 + rS)*K + k0 + cS, S + 16384 + q*8192 + offW);
        __syncthreads();
        #pragma unroll
        for(int ks=0;ks<4;ks++){
            int co = (ks*32 + l4*8) ^ sx;
            long af[4], bfr[4];
            #pragma unroll
            for(int mi=0;mi<4;mi++) af[mi] = *(const long*)(S + (wr*64+mi*16+l15)*128 + co);
            #pragma unroll
            for(int ni=0;ni<4;ni++) bfr[ni] = *(const long*)(S + 16384 + (wc*64+ni*16+l15)*128 + co);
            #pragma unroll
            for(int mi=0;mi<4;mi++)
                #pragma unroll
                for(int ni=0;ni<4;ni++)
                    acc[mi][ni] = mfma8(af[mi], bfr[ni], acc[mi][ni]);
        }
    }
    bf16* pz = part + (size_t)blockIdx.z*M*N;
    #pragma unroll
    for(int mi=0;mi<4;mi++)
        #pragma unroll
        for(int ni=0;ni<4;ni++){
            int col = n0 + wc*64 + ni*16 + l15;
            #pragma unroll
            for(int j=0;j<4;j++){
                int row = m0 + wr*64 + mi*16 + l4*4 + j;
                pz[(size_t)row*N + col] = (bf16)acc[mi][ni][j];
            }
        }
}

// reduce SPLIT bf16 partials + bias + ELU -> bf16, output SWIZZLED for c2's gld16 read
__global__ void k_c1fin(const bf16* __restrict__ part, const float* __restrict__ bias,
                        bf16* __restrict__ out){
    const size_t MN = (size_t)B_*512;
    size_t e0 = ((size_t)blockIdx.x*256 + threadIdx.x)*4;
    bf16x4 p0 = *(const bf16x4*)(part + e0);
    bf16x4 p1 = *(const bf16x4*)(part + MN + e0);
    bf16x4 p2 = *(const bf16x4*)(part + 2*MN + e0);
    bf16x4 p3 = *(const bf16x4*)(part + 3*MN + e0);
    f32x4 bb = *(const f32x4*)(bias + (e0 & 511));
    const float ds = 1.0f/(FP8SC*FP8SC);
    float s0 = ((float)p0[0]+(float)p1[0]+(float)p2[0]+(float)p3[0])*ds + bb[0];
    float s1 = ((float)p0[1]+(float)p1[1]+(float)p2[1]+(float)p3[1])*ds + bb[1];
    float s2 = ((float)p0[2]+(float)p1[2]+(float)p2[2]+(float)p3[2])*ds + bb[2];
    float s3 = ((float)p0[3]+(float)p1[3]+(float)p2[3]+(float)p3[3])*ds + bb[3];
    unsigned long long u = pack4_(eluf_(s0), eluf_(s1), eluf_(s2), eluf_(s3));
    int row = (int)(e0 >> 9);
    int ob = swzk_(row, (int)(e0 & 511) * 2);
    *(unsigned long long*)((char*)out + (size_t)row*1024 + ob) = u;
}

// ---------------- bf16 GEMM with global_load_lds staging + baked swizzle (c2, c3) ----------------
// A [M][K] bf16 (swizzled rows), Bt [N][K] bf16 (swizzled rows). BK=128. 256 threads.
// SWZOUT: write output rows swizzled (consumed by a downstream gld16 GEMM).
template<int BN, bool SWZOUT>
__global__ __launch_bounds__(256,2) void k_gemm_g(const bf16* __restrict__ A, const bf16* __restrict__ Bt,
        const float* __restrict__ bias, bf16* __restrict__ out, int M, int N, int K)
{
    __shared__ unsigned char S[32768 + BN*256];   // A pages then B pages; rows = 256 B
    int tid=threadIdx.x, w=tid>>6, lane=tid&63, l15=lane&15, l4=lane>>4;
    int m0 = blockIdx.y*128, n0 = blockIdx.x*BN;
    constexpr int MI = (BN==128)?4:2;
    int wr = (BN==128)? (w>>1) : w;
    int wc = (BN==128)? (w&1) : 0;
    int offT = tid*16;                 // 4-KB page per 16 rows
    int rS = offT >> 8, cS = offT & 255;
    f32x4 acc[MI][4];
    #pragma unroll
    for(int mi=0;mi<MI;mi++)
        #pragma unroll
        for(int ni=0;ni<4;ni++) acc[mi][ni] = (f32x4){0.f,0.f,0.f,0.f};

    int sx = (l15&7)<<4;

    for (int k0=0; k0<K; k0+=128){
        __syncthreads();
        #pragma unroll
        for (int q=0;q<8;q++)
            gld16_((const char*)A + ((size_t)(m0 + q*16 + rS)*K + k0)*2 + cS, S + q*4096 + offT);
        #pragma unroll
        for (int q=0;q<BN/16;q++)
            gld16_((const char*)Bt + ((size_t)(n0 + q*16 + rS)*K + k0)*2 + cS, S + 32768 + q*4096 + offT);
        __syncthreads();
        #pragma unroll
        for(int ks=0;ks<4;ks++){
            int co = (ks*32 + l4*8)*2;
            co = (co & ~127) | ((co & 127) ^ sx);
            bf16x8 af[MI], bfr[4];
            #pragma unroll
            for(int mi=0;mi<MI;mi++) af[mi] = *(const bf16x8*)(S + (wr*(MI*16)+mi*16+l15)*256 + co);
            #pragma unroll
            for(int ni=0;ni<4;ni++) bfr[ni] = *(const bf16x8*)(S + 32768 + (wc*64+ni*16+l15)*256 + co);
            #pragma unroll
            for(int mi=0;mi<MI;mi++)
                #pragma unroll
                for(int ni=0;ni<4;ni++)
                    acc[mi][ni] = mfma16(af[mi], bfr[ni], acc[mi][ni]);
        }
    }
    #pragma unroll
    for(int mi=0;mi<MI;mi++)
        #pragma unroll
        for(int ni=0;ni<4;ni++){
            int col = n0 + wc*64 + ni*16 + l15;
            float bc = bias[col];
            #pragma unroll
            for(int j=0;j<4;j++){
                int row = m0 + wr*(MI*16) + mi*16 + l4*4 + j;
                float v = eluf_(acc[mi][ni][j] + bc);
                if (SWZOUT){
                    int ob = swzk_(row, col*2);
                    *(bf16*)((char*)out + (size_t)row*N*2 + ob) = (bf16)v;
                } else {
                    out[(size_t)row*N + col] = (bf16)v;
                }
            }
        }
}

// ---------------- merged tails (unchanged) ----------------
__global__ __launch_bounds__(256,2) void k_tails(const bf16* __restrict__ c3o,
    const float* __restrict__ c4w, const float* __restrict__ c4b,
    const float* __restrict__ c5w, const float* __restrict__ c5b,
    const float* __restrict__ clw, const float* __restrict__ clb,
    const float* __restrict__ ctw, const float* __restrict__ ctb,
    const bf16* __restrict__ xtb,
    const float* __restrict__ u1w, const float* __restrict__ u1b,
    const float* __restrict__ u2w, const float* __restrict__ u2b,
    const float* __restrict__ u3w, const float* __restrict__ u3b,
    const float* __restrict__ u4w, const float* __restrict__ u4b,
    const float* __restrict__ tlw, const float* __restrict__ tlb,
    const float* __restrict__ utw, const float* __restrict__ utb, float* __restrict__ outp)
{
    __shared__ char A[58880];
    int tid = threadIdx.x, blk = blockIdx.x;
    int r0 = (blk>>1)*32;
    if ((blk & 1) == 0){
        float (*sA)[260] = (float(*)[260])A;
        float (*sB)[132] = (float(*)[132])(A + 33280);
        float (*sC)[68]  = (float(*)[68])(A + 50176);
        for (int v=tid; v<32*64; v+=256){
            int r=v>>6, c=(v&63)*4;
            bf16x4 x = *(const bf16x4*)(c3o + (size_t)(r0+r)*256 + c);
            sA[r][c]=(float)x[0]; sA[r][c+1]=(float)x[1]; sA[r][c+2]=(float)x[2]; sA[r][c+3]=(float)x[3];
        }
        __syncthreads();
        {
            int j = tid&127, rb = tid>>7;
            float acc[16];
            #pragma unroll
            for (int i=0;i<16;i++) acc[i]=c4b[j];
            #pragma unroll 4
            for (int h=0;h<256;h++){
                float wv = c4w[h*128+j];
                #pragma unroll
                for (int i=0;i<16;i++) acc[i] += sA[2*i+rb][h]*wv;
            }
            #pragma unroll
            for (int i=0;i<16;i++) sB[2*i+rb][j] = eluf_(acc[i]);
        }
        __syncthreads();
        {
            int j = tid&63, rb = tid>>6;
            float acc[8];
            #pragma unroll
            for (int i=0;i<8;i++) acc[i]=c5b[j];
            #pragma unroll 4
            for (int h=0;h<128;h++){
                float wv = c5w[h*64+j];
                #pragma unroll
                for (int i=0;i<8;i++) acc[i] += sB[4*i+rb][h]*wv;
            }
            #pragma unroll
            for (int i=0;i<8;i++) sC[4*i+rb][j] = eluf_(acc[i]);
        }
        __syncthreads();
        if (tid < 32){
            float r1 = clb[0], r2 = ctb[0];
            #pragma unroll 8
            for (int k=0;k<64;k++){ float v = sC[tid][k]; r1 += v*clw[k]; r2 += v*ctw[k]; }
            int row = r0 + tid;
            outp[row] = r1;
            outp[B_ + row] = sigmoidf_(r1);
            outp[(size_t)2*B_ + row] = r2;
        }
    } else {
        float (*sA)[132] = (float(*)[132])A;
        float (*sB)[132] = (float(*)[132])(A + 16896);
        float (*sC)[68]  = (float(*)[68])(A + 33792);
        float (*sD)[36]  = (float(*)[36])(A + 42496);
        float (*sE)[20]  = (float(*)[20])(A + 47104);
        for (int v=tid; v<32*32; v+=256){
            int r=v>>5, c=(v&31)*4;
            bf16x4 x = *(const bf16x4*)(xtb + (size_t)(r0+r)*128 + c);
            sA[r][c]=(float)x[0]; sA[r][c+1]=(float)x[1]; sA[r][c+2]=(float)x[2]; sA[r][c+3]=(float)x[3];
        }
        __syncthreads();
        {
            int j = tid&127, rb = tid>>7;
            float acc[16];
            #pragma unroll
            for (int i=0;i<16;i++) acc[i]=u1b[j];
            #pragma unroll 4
            for (int h=0;h<128;h++){
                float wv = u1w[h*128+j];
                #pragma unroll
                for (int i=0;i<16;i++) acc[i] += sA[2*i+rb][h]*wv;
            }
            #pragma unroll
            for (int i=0;i<16;i++) sB[2*i+rb][j] = eluf_(acc[i]);
        }
        __syncthreads();
        {
            int j = tid&63, rb = tid>>6;
            float acc[8];
            #pragma unroll
            for (int i=0;i<8;i++) acc[i]=u2b[j];
            #pragma unroll 4
            for (int h=0;h<128;h++){
                float wv = u2w[h*64+j];
                #pragma unroll
                for (int i=0;i<8;i++) acc[i] += sB[4*i+rb][h]*wv;
            }
            #pragma unroll
            for (int i=0;i<8;i++) sC[4*i+rb][j] = eluf_(acc[i]);
        }
        __syncthreads();
        {
            int j = tid&31, rb = tid>>5;
            float acc[4];
            #pragma unroll
            for (int i=0;i<4;i++) acc[i]=u3b[j];
            #pragma unroll 4
            for (int h=0;h<64;h++){
                float wv = u3w[h*32+j];
                #pragma unroll
                for (int i=0;i<4;i++) acc[i] += sC[8*i+rb][h]*wv;
            }
            #pragma unroll
            for (int i=0;i<4;i++) sD[8*i+rb][j] = eluf_(acc[i]);
        }
        __syncthreads();
        {
            int j = tid&15, rb = tid>>4;
            float acc0=u4b[j], acc1=u4b[j];
            #pragma unroll 4
            for (int h=0;h<32;h++){
                float wv = u4w[h*16+j];
                acc0 += sD[rb][h]*wv;
                acc1 += sD[16+rb][h]*wv;
            }
            sE[rb][j] = eluf_(acc0);
            sE[16+rb][j] = eluf_(acc1);
        }
        __syncthreads();
        if (tid < 32){
            float r1 = tlb[0], r2 = utb[0];
            #pragma unroll
            for (int k=0;k<16;k++){ float v = sE[tid][k]; r1 += v*tlw[k]; r2 += v*utw[k]; }
            int row = r0 + tid;
            outp[(size_t)3*B_ + row] = r1;
            outp[(size_t)4*B_ + row] = sigmoidf_(r1);
            outp[(size_t)5*B_ + row] = r2;
        }
    }
}

extern "C" void kernel_launch(void* const* d_in, const int* in_sizes, int n_in,
                              void* d_out, int out_size, void* d_ws, size_t ws_size,
                              hipStream_t stream) {
    const float* feat=(const float*)d_in[0];
    const float* emb =(const float*)d_in[2];
    const float* t_w =(const float*)d_in[3]; const float* t_b=(const float*)d_in[4];
    const float* qw  =(const float*)d_in[5]; const float* qb =(const float*)d_in[6];
    const float* kw  =(const float*)d_in[7]; const float* kb =(const float*)d_in[8];
    const float* vw  =(const float*)d_in[9]; const float* vb =(const float*)d_in[10];
    const float* a1w =(const float*)d_in[11];
    const float* a2w =(const float*)d_in[12]; const float* a2b=(const float*)d_in[13];
    const float* a3w =(const float*)d_in[14];
    const float* c1w =(const float*)d_in[15]; const float* c1b=(const float*)d_in[16];
    const float* c2w =(const float*)d_in[17]; const float* c2b=(const float*)d_in[18];
    const float* c3w =(const float*)d_in[19]; const float* c3b=(const float*)d_in[20];
    const float* c4w =(const float*)d_in[21]; const float* c4b=(const float*)d_in[22];
    const float* c5w =(const float*)d_in[23]; const float* c5b=(const float*)d_in[24];
    const float* clw =(const float*)d_in[25]; const float* clb=(const float*)d_in[26];
    const float* ctw =(const float*)d_in[27]; const float* ctb=(const float*)d_in[28];
    const float* u1w =(const float*)d_in[29]; const float* u1b=(const float*)d_in[30];
    const float* u2w =(const float*)d_in[31]; const float* u2b=(const float*)d_in[32];
    const float* u3w =(const float*)d_in[33]; const float* u3b=(const float*)d_in[34];
    const float* u4w =(const float*)d_in[35]; const float* u4b=(const float*)d_in[36];
    const float* tlw =(const float*)d_in[37]; const float* tlb=(const float*)d_in[38];
    const float* utw =(const float*)d_in[39]; const float* utb=(const float*)d_in[40];
    float* outp = (float*)d_out;

    char* ws = (char*)d_ws;
    size_t off = 0;
    auto alloc = [&](size_t bytes)->char*{ char* p = ws + off; off += (bytes + 255) & ~(size_t)255; return p; };
    unsigned char* xxb = (unsigned char*)alloc((size_t)B_*KC_);
    bf16* part   = (bf16*)alloc((size_t)SPLIT_*B_*512*2);
    float* attg  = (float*)alloc((size_t)B_*FP*4);
    bf16* xtb    = (bf16*)alloc((size_t)B_*128*2);
    bf16* cbuf1  = (bf16*)alloc((size_t)B_*512*2);
    bf16* mextT  = (bf16*)alloc(144*128*2);
    bf16* wvT    = (bf16*)alloc(128*128*2);
    bf16* wa2t   = (bf16*)alloc(128*128*2);
    unsigned char* c1wtk8 = (unsigned char*)alloc((size_t)512*KC_);
    bf16* c2wt   = (bf16*)alloc((size_t)512*512*2);
    bf16* c3wt   = (bf16*)alloc((size_t)512*256*2);
    float* sigt  = (float*)alloc(128*4);
    float* cconst= (float*)alloc(4);
    bf16* cbuf2 = (bf16*)(xxb);
    bf16* cbuf3 = (bf16*)(xxb + (16u<<20));
    (void)ws_size; (void)in_sizes; (void)n_in; (void)out_size;

    k_prep_all<<<426,256,0,stream>>>(qw,qb,kw,kb,t_w,t_b,a1w, vw, a2w, c2w, c3w,
                                     mextT, sigt, cconst, wvT, wa2t, c2wt, c3wt);

    k_gk<<<13568,256,0,stream>>>(c1w, c1wtk8, feat, emb, wa2t, a2b, a3w, sigt, attg);

    k_attn2<<<B_,512,0,stream>>>(feat,emb,mextT,wvT,vb,cconst,attg, xxb, xtb);

    k_gemm_fp8<<<dim3(2,64,SPLIT_),512,0,stream>>>(xxb, c1wtk8, part, B_,512,KC_, KC_/SPLIT_);
    k_c1fin<<<4096,256,0,stream>>>(part, c1b, cbuf1);

    k_gemm_g<128,true><<<dim3(4,64),256,0,stream>>>(cbuf1, c2wt, c2b, cbuf2, B_,512,512);
    k_gemm_g<64,false><<<dim3(4,64),256,0,stream>>>(cbuf2, c3wt, c3b, cbuf3, B_,256,512);

    k_tails<<<512,256,0,stream>>>(cbuf3,c4w,c4b,c5w,c5b,clw,clb,ctw,ctb,
                                  xtb,u1w,u1b,u2w,u2b,u3w,u3b,u4w,u4b,tlw,tlb,utw,utb,outp);
}